// Round 1
// baseline (3341.063 us; speedup 1.0000x reference)
//
#include <hip/hip_runtime.h>
#include <math.h>

#define BATCH 8
#define SEQ   1024
#define HID_  768
#define HEADS 12
#define LORA  256
#define HDIM  64

// scale = HID ** -0.5 = 768 ** -0.5
#define SCALE 0.03608439182435161f

// ---------------------------------------------------------------------------
// Stage 1: t[b,h,n,e] = sum_l Wa[h,e,l] * (sum_d hs[b,n,d] * Wt[h,l,d])
// grid = B*HEADS*(SEQ/64), block = 256.
// Per block: 64 n-rows for one (b,h). LoRA dim processed in 4 chunks of 64 so
// t1 lives only in LDS. LDS: hs[64][36] + wt[64][36] + t1[64][68] + wa[64][68]
// = 53,248 B (< 64 KB static cap).
// ---------------------------------------------------------------------------
__global__ __launch_bounds__(256) void proj_kernel(
    const float* __restrict__ hs,   // [B][SEQ][HID]
    const float* __restrict__ Wt,   // [HEADS][LORA][HID]
    const float* __restrict__ Wa,   // [HEADS][HDIM][LORA]
    float* __restrict__ t)          // [B][HEADS][SEQ][HDIM]
{
    const int bid   = blockIdx.x;
    const int ntile = bid & 15;               // SEQ/64 = 16 tiles
    const int h     = (bid >> 4) % HEADS;
    const int b     = bid / (16 * HEADS);
    const int n0    = ntile * 64;
    const int tid   = threadIdx.x;

    __shared__ float lds_hs[64 * 36];   // [n][dd], d-chunk 32, stride 36
    __shared__ float lds_wt[64 * 36];   // [l][dd]
    __shared__ float lds_t1[64 * 68];   // [n][l-chunk], stride 68
    __shared__ float lds_wa[64 * 68];   // [e][l-chunk]

    // phase A mapping: thread owns 1 l, 16 n rows
    const int lq = tid & 63;
    const int nq = tid >> 6;
    // phase B mapping: thread owns 4 n rows x 4 e cols
    const int nt0 = (tid >> 4) * 4;
    const int e0  = (tid & 15) * 4;

    float acc2[4][4] = {{0.f,0.f,0.f,0.f},{0.f,0.f,0.f,0.f},
                        {0.f,0.f,0.f,0.f},{0.f,0.f,0.f,0.f}};

    const float* hs_b = hs + (size_t)b * SEQ * HID_;
    const float* Wt_h = Wt + (size_t)h * LORA * HID_;
    const float* Wa_h = Wa + (size_t)h * HDIM * LORA;

    for (int lc = 0; lc < 4; ++lc) {
        const int l0g = lc * 64;
        float acc[16];
        #pragma unroll
        for (int j = 0; j < 16; ++j) acc[j] = 0.f;

        for (int dc = 0; dc < HID_ / 32; ++dc) {
            const int d0 = dc * 32;
            __syncthreads();   // guard prior readers of lds_hs/lds_wt (and prior phase B)
            // cooperative load: hs chunk 64x32, wt chunk 64x32 (8 float4/thread total... 2 each)
            #pragma unroll
            for (int k = 0; k < 2; ++k) {
                int flat4 = tid + k * 256;        // 512 float4s
                int n  = flat4 >> 3;
                int c4 = (flat4 & 7) * 4;
                float4 v = *(const float4*)&hs_b[(size_t)(n0 + n) * HID_ + d0 + c4];
                *(float4*)&lds_hs[n * 36 + c4] = v;
            }
            #pragma unroll
            for (int k = 0; k < 2; ++k) {
                int flat4 = tid + k * 256;
                int l  = flat4 >> 3;
                int c4 = (flat4 & 7) * 4;
                float4 v = *(const float4*)&Wt_h[(size_t)(l0g + l) * HID_ + d0 + c4];
                *(float4*)&lds_wt[l * 36 + c4] = v;
            }
            __syncthreads();

            // phase A compute: acc[j] += Wt[l, d] * hs[n, d]
            #pragma unroll
            for (int dd = 0; dd < 32; dd += 4) {
                float4 w4 = *(float4*)&lds_wt[lq * 36 + dd];
                #pragma unroll
                for (int j = 0; j < 16; ++j) {
                    float4 h4 = *(float4*)&lds_hs[(nq * 16 + j) * 36 + dd];
                    acc[j] += w4.x * h4.x + w4.y * h4.y + w4.z * h4.z + w4.w * h4.w;
                }
            }
        }

        // write t1 chunk to LDS: t1[n][lq]
        #pragma unroll
        for (int j = 0; j < 16; ++j)
            lds_t1[(nq * 16 + j) * 68 + lq] = acc[j];

        // load Wa chunk: 64 e x 64 l
        #pragma unroll
        for (int k = 0; k < 4; ++k) {
            int flat4 = tid + k * 256;            // 1024 float4s
            int e  = flat4 >> 4;
            int c4 = (flat4 & 15) * 4;
            float4 v = *(const float4*)&Wa_h[(size_t)e * LORA + l0g + c4];
            *(float4*)&lds_wa[e * 68 + c4] = v;
        }
        __syncthreads();

        // phase B: acc2[n][e] += t1[n][l] * Wa[e][l]
        #pragma unroll
        for (int l = 0; l < 64; l += 4) {
            float4 t14[4], wa4[4];
            #pragma unroll
            for (int ii = 0; ii < 4; ++ii)
                t14[ii] = *(float4*)&lds_t1[(nt0 + ii) * 68 + l];
            #pragma unroll
            for (int ee = 0; ee < 4; ++ee)
                wa4[ee] = *(float4*)&lds_wa[(e0 + ee) * 68 + l];
            #pragma unroll
            for (int ii = 0; ii < 4; ++ii) {
                #pragma unroll
                for (int ee = 0; ee < 4; ++ee) {
                    acc2[ii][ee] += t14[ii].x * wa4[ee].x + t14[ii].y * wa4[ee].y
                                  + t14[ii].z * wa4[ee].z + t14[ii].w * wa4[ee].w;
                }
            }
        }
    }

    // write t tile
    float* t_out = t + (((size_t)b * HEADS + h) * SEQ + n0) * HDIM;
    #pragma unroll
    for (int ii = 0; ii < 4; ++ii) {
        float4 v = {acc2[ii][0], acc2[ii][1], acc2[ii][2], acc2[ii][3]};
        *(float4*)&t_out[(size_t)(nt0 + ii) * HDIM + e0] = v;
    }
}

// ---------------------------------------------------------------------------
// Stage 2: flash-style attention, q = k = v = t.
// grid = B*HEADS*(SEQ/64), block = 256. One block: 64 i-rows of one (b,h).
// Online softmax over 16 j-tiles of 64. Thread owns 4x4 tiles in both the
// S phase (4 i x 4 j) and the O phase (4 i x 4 e); P goes through LDS.
// ---------------------------------------------------------------------------
__global__ __launch_bounds__(256) void attn_kernel(
    const float* __restrict__ t,    // [B][HEADS][SEQ][HDIM]
    const int* __restrict__ mask,   // [B][SEQ]
    float* __restrict__ out)        // [B][SEQ][HEADS*HDIM]
{
    const int bid   = blockIdx.x;
    const int itile = bid & 15;
    const int h     = (bid >> 4) % HEADS;
    const int b     = bid / (16 * HEADS);
    const int i0    = itile * 64;
    const int tid   = threadIdx.x;

    __shared__ float lds_ti[64 * 68];
    __shared__ float lds_tj[64 * 68];
    __shared__ float lds_p [64 * 68];
    __shared__ int   lds_mask[64];

    const int it0 = (tid >> 4) * 4;   // i rows (shared with O phase)
    const int jt0 = (tid & 15) * 4;   // j cols in S phase
    const int e0  = jt0;              // e cols in O phase

    const float* tb = t + ((size_t)b * HEADS + h) * SEQ * HDIM;

    // load ti tile
    #pragma unroll
    for (int k = 0; k < 4; ++k) {
        int flat4 = tid + k * 256;
        int r  = flat4 >> 4;
        int c4 = (flat4 & 15) * 4;
        *(float4*)&lds_ti[r * 68 + c4] = *(const float4*)&tb[(size_t)(i0 + r) * HDIM + c4];
    }

    float m[4], lsum[4], o[4][4];
    #pragma unroll
    for (int ii = 0; ii < 4; ++ii) {
        m[ii] = -INFINITY; lsum[ii] = 0.f;
        #pragma unroll
        for (int ee = 0; ee < 4; ++ee) o[ii][ee] = 0.f;
    }

    for (int jt = 0; jt < 16; ++jt) {
        const int j0 = jt * 64;
        __syncthreads();   // previous iteration's readers of lds_tj / lds_p done
        #pragma unroll
        for (int k = 0; k < 4; ++k) {
            int flat4 = tid + k * 256;
            int r  = flat4 >> 4;
            int c4 = (flat4 & 15) * 4;
            *(float4*)&lds_tj[r * 68 + c4] = *(const float4*)&tb[(size_t)(j0 + r) * HDIM + c4];
        }
        if (tid < 64) lds_mask[tid] = mask[(size_t)b * SEQ + j0 + tid];
        __syncthreads();

        // S = ti . tj^T  (4x4 per thread)
        float s[4][4] = {{0.f,0.f,0.f,0.f},{0.f,0.f,0.f,0.f},
                         {0.f,0.f,0.f,0.f},{0.f,0.f,0.f,0.f}};
        #pragma unroll
        for (int e = 0; e < 64; e += 4) {
            float4 a4[4], b4[4];
            #pragma unroll
            for (int ii = 0; ii < 4; ++ii)
                a4[ii] = *(float4*)&lds_ti[(it0 + ii) * 68 + e];
            #pragma unroll
            for (int jj = 0; jj < 4; ++jj)
                b4[jj] = *(float4*)&lds_tj[(jt0 + jj) * 68 + e];
            #pragma unroll
            for (int ii = 0; ii < 4; ++ii) {
                #pragma unroll
                for (int jj = 0; jj < 4; ++jj) {
                    s[ii][jj] += a4[ii].x * b4[jj].x + a4[ii].y * b4[jj].y
                               + a4[ii].z * b4[jj].z + a4[ii].w * b4[jj].w;
                }
            }
        }

        bool jm[4];
        #pragma unroll
        for (int jj = 0; jj < 4; ++jj) jm[jj] = (lds_mask[jt0 + jj] == 0);
        #pragma unroll
        for (int ii = 0; ii < 4; ++ii) {
            #pragma unroll
            for (int jj = 0; jj < 4; ++jj)
                s[ii][jj] = jm[jj] ? -INFINITY : s[ii][jj] * SCALE;
        }

        // online softmax update; rows live in 16 consecutive lanes (width=16 shfl)
        float p[4][4];
        #pragma unroll
        for (int ii = 0; ii < 4; ++ii) {
            float tmax = fmaxf(fmaxf(s[ii][0], s[ii][1]), fmaxf(s[ii][2], s[ii][3]));
            #pragma unroll
            for (int w = 1; w < 16; w <<= 1)
                tmax = fmaxf(tmax, __shfl_xor(tmax, w, 16));
            float mnew = fmaxf(m[ii], tmax);
            float alpha;
            if (mnew == -INFINITY) {   // all masked so far: keep zeros
                alpha = 1.f;
                #pragma unroll
                for (int jj = 0; jj < 4; ++jj) p[ii][jj] = 0.f;
            } else {
                alpha = (m[ii] == -INFINITY) ? 0.f : __expf(m[ii] - mnew);
                #pragma unroll
                for (int jj = 0; jj < 4; ++jj)
                    p[ii][jj] = jm[jj] ? 0.f : __expf(s[ii][jj] - mnew);
            }
            float rs = p[ii][0] + p[ii][1] + p[ii][2] + p[ii][3];
            #pragma unroll
            for (int w = 1; w < 16; w <<= 1)
                rs += __shfl_xor(rs, w, 16);
            m[ii] = mnew;
            lsum[ii] = lsum[ii] * alpha + rs;
            #pragma unroll
            for (int ee = 0; ee < 4; ++ee) o[ii][ee] *= alpha;
        }

        #pragma unroll
        for (int ii = 0; ii < 4; ++ii) {
            float4 pv = {p[ii][0], p[ii][1], p[ii][2], p[ii][3]};
            *(float4*)&lds_p[(it0 + ii) * 68 + jt0] = pv;
        }
        __syncthreads();

        // O += P . tj   (4 i x 4 e per thread)
        #pragma unroll
        for (int j = 0; j < 64; j += 4) {
            float4 r0 = *(float4*)&lds_tj[(j + 0) * 68 + e0];
            float4 r1 = *(float4*)&lds_tj[(j + 1) * 68 + e0];
            float4 r2 = *(float4*)&lds_tj[(j + 2) * 68 + e0];
            float4 r3 = *(float4*)&lds_tj[(j + 3) * 68 + e0];
            #pragma unroll
            for (int ii = 0; ii < 4; ++ii) {
                float4 p4 = *(float4*)&lds_p[(it0 + ii) * 68 + j];
                o[ii][0] += p4.x * r0.x + p4.y * r1.x + p4.z * r2.x + p4.w * r3.x;
                o[ii][1] += p4.x * r0.y + p4.y * r1.y + p4.z * r2.y + p4.w * r3.y;
                o[ii][2] += p4.x * r0.z + p4.y * r1.z + p4.z * r2.z + p4.w * r3.z;
                o[ii][3] += p4.x * r0.w + p4.y * r1.w + p4.z * r2.w + p4.w * r3.w;
            }
        }
    }

    // epilogue: normalize and write out[b][n][h*64 + e]
    #pragma unroll
    for (int ii = 0; ii < 4; ++ii) {
        float inv = (lsum[ii] > 0.f) ? 1.f / lsum[ii] : 0.f;
        float4 v = {o[ii][0] * inv, o[ii][1] * inv, o[ii][2] * inv, o[ii][3] * inv};
        *(float4*)&out[((size_t)b * SEQ + i0 + it0 + ii) * (HEADS * HDIM) + h * HDIM + e0] = v;
    }
}

extern "C" void kernel_launch(void* const* d_in, const int* in_sizes, int n_in,
                              void* d_out, int out_size, void* d_ws, size_t ws_size,
                              hipStream_t stream) {
    const float* hs   = (const float*)d_in[0];
    const int*   mask = (const int*)d_in[1];
    const float* Wt   = (const float*)d_in[2];
    const float* Wa   = (const float*)d_in[3];
    float* out = (float*)d_out;
    float* t   = (float*)d_ws;   // [B][HEADS][SEQ][HDIM] = 25.2 MB scratch

    dim3 grid(BATCH * HEADS * (SEQ / 64));
    proj_kernel<<<grid, 256, 0, stream>>>(hs, Wt, Wa, t);
    attn_kernel<<<grid, 256, 0, stream>>>(t, mask, out);
}

// Round 2
// 1491.140 us; speedup vs baseline: 2.2406x; 2.2406x over previous
//
#include <hip/hip_runtime.h>
#include <math.h>

#define BATCH 8
#define SEQ   1024
#define HID_  768
#define HEADS 12
#define LORA  256
#define HDIM  64

// scale = HID ** -0.5
#define SCALE 0.03608439182435161f

typedef short bf16x8 __attribute__((ext_vector_type(8)));
typedef float f32x4  __attribute__((ext_vector_type(4)));
typedef unsigned short ushort_t;

__device__ __forceinline__ unsigned short f2bf(float x) {
    unsigned u = __float_as_uint(x);
    u += 0x7fff + ((u >> 16) & 1);          // round-to-nearest-even
    return (unsigned short)(u >> 16);
}
__device__ __forceinline__ float bf2f(unsigned short h) {
    return __uint_as_float(((unsigned)h) << 16);
}

// async global->LDS, 16B per lane, LDS dest = uniform base + lane*16
#define GLD16(g, l) __builtin_amdgcn_global_load_lds( \
    (const __attribute__((address_space(1))) void*)(g), \
    (__attribute__((address_space(3))) void*)(l), 16, 0, 0)

// ---------------------------------------------------------------------------
// Pre-pass: split fp32 -> (hi, lo) bf16.  lo = bf16(x - float(hi)).
// ---------------------------------------------------------------------------
__global__ __launch_bounds__(256) void split_kernel(
    const float4* __restrict__ src, ushort4* __restrict__ hi,
    ushort4* __restrict__ lo, int n4)
{
    int stride = gridDim.x * blockDim.x;
    for (int i = blockIdx.x * blockDim.x + threadIdx.x; i < n4; i += stride) {
        float4 v = src[i];
        ushort4 h, l;
        h.x = f2bf(v.x); l.x = f2bf(v.x - bf2f(h.x));
        h.y = f2bf(v.y); l.y = f2bf(v.y - bf2f(h.y));
        h.z = f2bf(v.z); l.z = f2bf(v.z - bf2f(h.z));
        h.w = f2bf(v.w); l.w = f2bf(v.w - bf2f(h.w));
        hi[i] = h; lo[i] = l;
    }
}

// ---------------------------------------------------------------------------
// Projection via bf16x3 MFMA (hi*hi + hi*lo + lo*hi ~= fp32 precision).
// grid = B*HEADS*(SEQ/128), block = 256 (4 waves).
// Per block: t[b,h, n0:n0+128, 0:64]. LoRA in 4 chunks of 64:
//   stage A: t1[128,64] = hs[128,768] . Wt_chunk^T   (K staged 64 at a time)
//   stage B: t  += t1 . Wa_chunk^T                   (t1 hi/lo via LDS)
// LDS 48KB, aliased between (hs,wt staging) and (t1,wa) phases.
// MFMA 16x16x32 bf16; A-frag: A[m=lane&15][k=(lane>>4)*8+j] (16B contig);
// C/D: col=lane&15, row=(lane>>4)*4+reg  (m89-verified layouts).
// ---------------------------------------------------------------------------
__global__ __launch_bounds__(256) void proj_mfma(
    const ushort_t* __restrict__ hs_hi, const ushort_t* __restrict__ hs_lo,
    const ushort_t* __restrict__ wt_hi, const ushort_t* __restrict__ wt_lo,
    const ushort_t* __restrict__ wa_hi, const ushort_t* __restrict__ wa_lo,
    float* __restrict__ t)
{
    __shared__ __attribute__((aligned(16))) char smem[49152];
    ushort_t* s_hsh = (ushort_t*)smem;             // [128][64]
    ushort_t* s_hsl = (ushort_t*)(smem + 16384);   // [128][64]
    ushort_t* s_wth = (ushort_t*)(smem + 32768);   // [64][64]
    ushort_t* s_wtl = (ushort_t*)(smem + 40960);   // [64][64]
    // phase-2 aliases (live only after stage-A reads complete)
    ushort_t* s_t1h = (ushort_t*)smem;             // [128][64]
    ushort_t* s_t1l = (ushort_t*)(smem + 16384);
    ushort_t* s_wah = (ushort_t*)(smem + 32768);   // [64][64]
    ushort_t* s_wal = (ushort_t*)(smem + 40960);

    const int bid   = blockIdx.x;
    const int ntile = bid & 7;                 // SEQ/128 = 8
    const int h     = (bid >> 3) % HEADS;
    const int b     = bid / (8 * HEADS);
    const int n0    = ntile * 128;
    const int tid   = threadIdx.x;
    const int w     = tid >> 6;                // wave 0..3
    const int lane  = tid & 63;
    const int q     = lane >> 4;               // quad 0..3
    const int mr    = lane & 15;
    const int lrow  = lane >> 3;               // staging: 8 lanes per 64-elem row
    const int lcol  = (lane & 7) * 8;

    const ushort_t* hsh_g = hs_hi + (size_t)b * SEQ * HID_;
    const ushort_t* hsl_g = hs_lo + (size_t)b * SEQ * HID_;
    const ushort_t* wth_g = wt_hi + (size_t)h * LORA * HID_;
    const ushort_t* wtl_g = wt_lo + (size_t)h * LORA * HID_;
    const ushort_t* wah_g = wa_hi + (size_t)h * HDIM * LORA;
    const ushort_t* wal_g = wa_lo + (size_t)h * HDIM * LORA;

    const f32x4 z4 = {0.f, 0.f, 0.f, 0.f};
    f32x4 accB[2][4];
    #pragma unroll
    for (int mt = 0; mt < 2; ++mt)
        #pragma unroll
        for (int et = 0; et < 4; ++et) accB[mt][et] = z4;

    for (int lc = 0; lc < 4; ++lc) {
        const int l0g = lc * 64;

        f32x4 accA[2][4];
        #pragma unroll
        for (int mt = 0; mt < 2; ++mt)
            #pragma unroll
            for (int lt = 0; lt < 4; ++lt) accA[mt][lt] = z4;

        // ---- stage A: K = 768 in 12 rounds of 64 ----
        for (int rd = 0; rd < 12; ++rd) {
            const int k0 = rd * 64;
            __syncthreads();   // prior readers of the aliased LDS are done
            #pragma unroll
            for (int tt = 0; tt < 4; ++tt) {   // hs rows: wave owns 32
                int r0 = w * 32 + tt * 8;
                GLD16(hsh_g + (size_t)(n0 + r0 + lrow) * HID_ + k0 + lcol, s_hsh + r0 * 64);
                GLD16(hsl_g + (size_t)(n0 + r0 + lrow) * HID_ + k0 + lcol, s_hsl + r0 * 64);
            }
            #pragma unroll
            for (int tt = 0; tt < 2; ++tt) {   // wt rows: wave owns 16
                int r0 = w * 16 + tt * 8;
                GLD16(wth_g + (size_t)(l0g + r0 + lrow) * HID_ + k0 + lcol, s_wth + r0 * 64);
                GLD16(wtl_g + (size_t)(l0g + r0 + lrow) * HID_ + k0 + lcol, s_wtl + r0 * 64);
            }
            __syncthreads();   // drains vmcnt -> staging visible

            #pragma unroll
            for (int ks = 0; ks < 2; ++ks) {
                bf16x8 ah[2], al[2], bh[4], bl[4];
                #pragma unroll
                for (int mt = 0; mt < 2; ++mt) {
                    int off = (w * 32 + mt * 16 + mr) * 64 + ks * 32 + q * 8;
                    ah[mt] = *(const bf16x8*)(s_hsh + off);
                    al[mt] = *(const bf16x8*)(s_hsl + off);
                }
                #pragma unroll
                for (int lt = 0; lt < 4; ++lt) {
                    int off = (lt * 16 + mr) * 64 + ks * 32 + q * 8;
                    bh[lt] = *(const bf16x8*)(s_wth + off);
                    bl[lt] = *(const bf16x8*)(s_wtl + off);
                }
                #pragma unroll
                for (int mt = 0; mt < 2; ++mt) {
                    #pragma unroll
                    for (int lt = 0; lt < 4; ++lt) {
                        accA[mt][lt] = __builtin_amdgcn_mfma_f32_16x16x32_bf16(ah[mt], bh[lt], accA[mt][lt], 0, 0, 0);
                        accA[mt][lt] = __builtin_amdgcn_mfma_f32_16x16x32_bf16(ah[mt], bl[lt], accA[mt][lt], 0, 0, 0);
                        accA[mt][lt] = __builtin_amdgcn_mfma_f32_16x16x32_bf16(al[mt], bh[lt], accA[mt][lt], 0, 0, 0);
                    }
                }
            }
        }
        __syncthreads();   // stage-A LDS reads done; safe to overwrite aliases

        // ---- t1 -> LDS as hi/lo bf16 (own-wave rows only) ----
        #pragma unroll
        for (int mt = 0; mt < 2; ++mt) {
            #pragma unroll
            for (int lt = 0; lt < 4; ++lt) {
                #pragma unroll
                for (int r = 0; r < 4; ++r) {
                    int nl = w * 32 + mt * 16 + q * 4 + r;   // C/D row
                    int ll = lt * 16 + mr;                   // C/D col
                    float v = accA[mt][lt][r];
                    unsigned short hv = f2bf(v);
                    s_t1h[nl * 64 + ll] = hv;
                    s_t1l[nl * 64 + ll] = f2bf(v - bf2f(hv));
                }
            }
        }
        // ---- stage Wa chunk [64 e][64 l] hi/lo ----
        #pragma unroll
        for (int tt = 0; tt < 2; ++tt) {
            int r0 = w * 16 + tt * 8;
            GLD16(wah_g + (size_t)(r0 + lrow) * LORA + l0g + lcol, s_wah + r0 * 64);
            GLD16(wal_g + (size_t)(r0 + lrow) * LORA + l0g + lcol, s_wal + r0 * 64);
        }
        __syncthreads();

        // ---- stage B: accB += t1 . Wa_chunk^T  (K = 64 = 2 halves) ----
        #pragma unroll
        for (int ks = 0; ks < 2; ++ks) {
            bf16x8 ah[2], al[2], bh[4], bl[4];
            #pragma unroll
            for (int mt = 0; mt < 2; ++mt) {
                int off = (w * 32 + mt * 16 + mr) * 64 + ks * 32 + q * 8;
                ah[mt] = *(const bf16x8*)(s_t1h + off);
                al[mt] = *(const bf16x8*)(s_t1l + off);
            }
            #pragma unroll
            for (int et = 0; et < 4; ++et) {
                int off = (et * 16 + mr) * 64 + ks * 32 + q * 8;
                bh[et] = *(const bf16x8*)(s_wah + off);
                bl[et] = *(const bf16x8*)(s_wal + off);
            }
            #pragma unroll
            for (int mt = 0; mt < 2; ++mt) {
                #pragma unroll
                for (int et = 0; et < 4; ++et) {
                    accB[mt][et] = __builtin_amdgcn_mfma_f32_16x16x32_bf16(ah[mt], bh[et], accB[mt][et], 0, 0, 0);
                    accB[mt][et] = __builtin_amdgcn_mfma_f32_16x16x32_bf16(ah[mt], bl[et], accB[mt][et], 0, 0, 0);
                    accB[mt][et] = __builtin_amdgcn_mfma_f32_16x16x32_bf16(al[mt], bh[et], accB[mt][et], 0, 0, 0);
                }
            }
        }
    }

    // ---- write t[b,h,n0:n0+128,0:64] fp32 ----
    float* tg = t + (((size_t)b * HEADS + h) * SEQ + n0) * HDIM;
    #pragma unroll
    for (int mt = 0; mt < 2; ++mt) {
        #pragma unroll
        for (int et = 0; et < 4; ++et) {
            #pragma unroll
            for (int r = 0; r < 4; ++r) {
                int nl = w * 32 + mt * 16 + q * 4 + r;
                int e  = et * 16 + mr;
                tg[(size_t)nl * HDIM + e] = accB[mt][et][r];
            }
        }
    }
}

// ---------------------------------------------------------------------------
// Stage 2: flash-style attention, q = k = v = t.  (unchanged from round 1)
// ---------------------------------------------------------------------------
__global__ __launch_bounds__(256) void attn_kernel(
    const float* __restrict__ t,    // [B][HEADS][SEQ][HDIM]
    const int* __restrict__ mask,   // [B][SEQ]
    float* __restrict__ out)        // [B][SEQ][HEADS*HDIM]
{
    const int bid   = blockIdx.x;
    const int itile = bid & 15;
    const int h     = (bid >> 4) % HEADS;
    const int b     = bid / (16 * HEADS);
    const int i0    = itile * 64;
    const int tid   = threadIdx.x;

    __shared__ float lds_ti[64 * 68];
    __shared__ float lds_tj[64 * 68];
    __shared__ float lds_p [64 * 68];
    __shared__ int   lds_mask[64];

    const int it0 = (tid >> 4) * 4;
    const int jt0 = (tid & 15) * 4;
    const int e0  = jt0;

    const float* tb = t + ((size_t)b * HEADS + h) * SEQ * HDIM;

    #pragma unroll
    for (int k = 0; k < 4; ++k) {
        int flat4 = tid + k * 256;
        int r  = flat4 >> 4;
        int c4 = (flat4 & 15) * 4;
        *(float4*)&lds_ti[r * 68 + c4] = *(const float4*)&tb[(size_t)(i0 + r) * HDIM + c4];
    }

    float m[4], lsum[4], o[4][4];
    #pragma unroll
    for (int ii = 0; ii < 4; ++ii) {
        m[ii] = -INFINITY; lsum[ii] = 0.f;
        #pragma unroll
        for (int ee = 0; ee < 4; ++ee) o[ii][ee] = 0.f;
    }

    for (int jt = 0; jt < 16; ++jt) {
        const int j0 = jt * 64;
        __syncthreads();
        #pragma unroll
        for (int k = 0; k < 4; ++k) {
            int flat4 = tid + k * 256;
            int r  = flat4 >> 4;
            int c4 = (flat4 & 15) * 4;
            *(float4*)&lds_tj[r * 68 + c4] = *(const float4*)&tb[(size_t)(j0 + r) * HDIM + c4];
        }
        if (tid < 64) lds_mask[tid] = mask[(size_t)b * SEQ + j0 + tid];
        __syncthreads();

        float s[4][4] = {{0.f,0.f,0.f,0.f},{0.f,0.f,0.f,0.f},
                         {0.f,0.f,0.f,0.f},{0.f,0.f,0.f,0.f}};
        #pragma unroll
        for (int e = 0; e < 64; e += 4) {
            float4 a4[4], b4[4];
            #pragma unroll
            for (int ii = 0; ii < 4; ++ii)
                a4[ii] = *(float4*)&lds_ti[(it0 + ii) * 68 + e];
            #pragma unroll
            for (int jj = 0; jj < 4; ++jj)
                b4[jj] = *(float4*)&lds_tj[(jt0 + jj) * 68 + e];
            #pragma unroll
            for (int ii = 0; ii < 4; ++ii) {
                #pragma unroll
                for (int jj = 0; jj < 4; ++jj) {
                    s[ii][jj] += a4[ii].x * b4[jj].x + a4[ii].y * b4[jj].y
                               + a4[ii].z * b4[jj].z + a4[ii].w * b4[jj].w;
                }
            }
        }

        bool jm[4];
        #pragma unroll
        for (int jj = 0; jj < 4; ++jj) jm[jj] = (lds_mask[jt0 + jj] == 0);
        #pragma unroll
        for (int ii = 0; ii < 4; ++ii) {
            #pragma unroll
            for (int jj = 0; jj < 4; ++jj)
                s[ii][jj] = jm[jj] ? -INFINITY : s[ii][jj] * SCALE;
        }

        float p[4][4];
        #pragma unroll
        for (int ii = 0; ii < 4; ++ii) {
            float tmax = fmaxf(fmaxf(s[ii][0], s[ii][1]), fmaxf(s[ii][2], s[ii][3]));
            #pragma unroll
            for (int wd = 1; wd < 16; wd <<= 1)
                tmax = fmaxf(tmax, __shfl_xor(tmax, wd, 16));
            float mnew = fmaxf(m[ii], tmax);
            float alpha;
            if (mnew == -INFINITY) {
                alpha = 1.f;
                #pragma unroll
                for (int jj = 0; jj < 4; ++jj) p[ii][jj] = 0.f;
            } else {
                alpha = (m[ii] == -INFINITY) ? 0.f : __expf(m[ii] - mnew);
                #pragma unroll
                for (int jj = 0; jj < 4; ++jj)
                    p[ii][jj] = jm[jj] ? 0.f : __expf(s[ii][jj] - mnew);
            }
            float rs = p[ii][0] + p[ii][1] + p[ii][2] + p[ii][3];
            #pragma unroll
            for (int wd = 1; wd < 16; wd <<= 1)
                rs += __shfl_xor(rs, wd, 16);
            m[ii] = mnew;
            lsum[ii] = lsum[ii] * alpha + rs;
            #pragma unroll
            for (int ee = 0; ee < 4; ++ee) o[ii][ee] *= alpha;
        }

        #pragma unroll
        for (int ii = 0; ii < 4; ++ii) {
            float4 pv = {p[ii][0], p[ii][1], p[ii][2], p[ii][3]};
            *(float4*)&lds_p[(it0 + ii) * 68 + jt0] = pv;
        }
        __syncthreads();

        #pragma unroll
        for (int j = 0; j < 64; j += 4) {
            float4 r0 = *(float4*)&lds_tj[(j + 0) * 68 + e0];
            float4 r1 = *(float4*)&lds_tj[(j + 1) * 68 + e0];
            float4 r2 = *(float4*)&lds_tj[(j + 2) * 68 + e0];
            float4 r3 = *(float4*)&lds_tj[(j + 3) * 68 + e0];
            #pragma unroll
            for (int ii = 0; ii < 4; ++ii) {
                float4 p4 = *(float4*)&lds_p[(it0 + ii) * 68 + j];
                o[ii][0] += p4.x * r0.x + p4.y * r1.x + p4.z * r2.x + p4.w * r3.x;
                o[ii][1] += p4.x * r0.y + p4.y * r1.y + p4.z * r2.y + p4.w * r3.y;
                o[ii][2] += p4.x * r0.z + p4.y * r1.z + p4.z * r2.z + p4.w * r3.z;
                o[ii][3] += p4.x * r0.w + p4.y * r1.w + p4.z * r2.w + p4.w * r3.w;
            }
        }
    }

    #pragma unroll
    for (int ii = 0; ii < 4; ++ii) {
        float inv = (lsum[ii] > 0.f) ? 1.f / lsum[ii] : 0.f;
        float4 v = {o[ii][0] * inv, o[ii][1] * inv, o[ii][2] * inv, o[ii][3] * inv};
        *(float4*)&out[((size_t)b * SEQ + i0 + it0 + ii) * (HEADS * HDIM) + h * HDIM + e0] = v;
    }
}

extern "C" void kernel_launch(void* const* d_in, const int* in_sizes, int n_in,
                              void* d_out, int out_size, void* d_ws, size_t ws_size,
                              hipStream_t stream) {
    const float* hs   = (const float*)d_in[0];
    const int*   mask = (const int*)d_in[1];
    const float* Wt   = (const float*)d_in[2];
    const float* Wa   = (const float*)d_in[3];
    float* out = (float*)d_out;

    // workspace layout (total 60,555,264 B):
    char* ws = (char*)d_ws;
    float*    t     = (float*)ws;                      // 25,165,824 B
    ushort_t* hs_hi = (ushort_t*)(ws + 25165824);      // 12,582,912 B
    ushort_t* hs_lo = (ushort_t*)(ws + 37748736);      // 12,582,912 B
    ushort_t* wt_hi = (ushort_t*)(ws + 50331648);      //  4,718,592 B
    ushort_t* wt_lo = (ushort_t*)(ws + 55050240);      //  4,718,592 B
    ushort_t* wa_hi = (ushort_t*)(ws + 59768832);      //    393,216 B
    ushort_t* wa_lo = (ushort_t*)(ws + 60162048);      //    393,216 B

    // pre-pass: fp32 -> hi/lo bf16 splits
    split_kernel<<<1024, 256, 0, stream>>>((const float4*)hs, (ushort4*)hs_hi,
                                           (ushort4*)hs_lo, (BATCH * SEQ * HID_) / 4);
    split_kernel<<<1024, 256, 0, stream>>>((const float4*)Wt, (ushort4*)wt_hi,
                                           (ushort4*)wt_lo, (HEADS * LORA * HID_) / 4);
    split_kernel<<<192, 256, 0, stream>>>((const float4*)Wa, (ushort4*)wa_hi,
                                          (ushort4*)wa_lo, (HEADS * HDIM * LORA) / 4);

    proj_mfma<<<BATCH * HEADS * (SEQ / 128), 256, 0, stream>>>(
        hs_hi, hs_lo, wt_hi, wt_lo, wa_hi, wa_lo, t);

    attn_kernel<<<BATCH * HEADS * (SEQ / 64), 256, 0, stream>>>(t, mask, out);
}

// Round 3
// 501.707 us; speedup vs baseline: 6.6594x; 2.9721x over previous
//
#include <hip/hip_runtime.h>
#include <math.h>

#define BATCH 8
#define SEQ   1024
#define HID_  768
#define HEADS 12
#define LORA  256
#define HDIM  64

// scale = HID ** -0.5
#define SCALE 0.03608439182435161f

typedef short bf16x8 __attribute__((ext_vector_type(8)));
typedef float f32x4  __attribute__((ext_vector_type(4)));
typedef unsigned short ushort_t;
typedef unsigned short ushort8_t __attribute__((ext_vector_type(8)));

__device__ __forceinline__ unsigned short f2bf(float x) {
    unsigned u = __float_as_uint(x);
    u += 0x7fff + ((u >> 16) & 1);          // round-to-nearest-even
    return (unsigned short)(u >> 16);
}
__device__ __forceinline__ float bf2f(unsigned short h) {
    return __uint_as_float(((unsigned)h) << 16);
}

// async global->LDS, 16B per lane, LDS dest = uniform base + lane*16
#define GLD16(g, l) __builtin_amdgcn_global_load_lds( \
    (const __attribute__((address_space(1))) void*)(g), \
    (__attribute__((address_space(3))) void*)(l), 16, 0, 0)

// ---------------------------------------------------------------------------
// Pre-pass: split fp32 -> (hi, lo) bf16.  lo = bf16(x - float(hi)).
// ---------------------------------------------------------------------------
__global__ __launch_bounds__(256) void split_kernel(
    const float4* __restrict__ src, ushort4* __restrict__ hi,
    ushort4* __restrict__ lo, int n4)
{
    int stride = gridDim.x * blockDim.x;
    for (int i = blockIdx.x * blockDim.x + threadIdx.x; i < n4; i += stride) {
        float4 v = src[i];
        ushort4 h, l;
        h.x = f2bf(v.x); l.x = f2bf(v.x - bf2f(h.x));
        h.y = f2bf(v.y); l.y = f2bf(v.y - bf2f(h.y));
        h.z = f2bf(v.z); l.z = f2bf(v.z - bf2f(h.z));
        h.w = f2bf(v.w); l.w = f2bf(v.w - bf2f(h.w));
        hi[i] = h; lo[i] = l;
    }
}

// ---------------------------------------------------------------------------
// Projection via bf16x3 MFMA (unchanged structure from round 2); epilogue now
// writes t as hi/lo bf16 instead of fp32 (attention consumes bf16 directly).
// ---------------------------------------------------------------------------
__global__ __launch_bounds__(256) void proj_mfma(
    const ushort_t* __restrict__ hs_hi, const ushort_t* __restrict__ hs_lo,
    const ushort_t* __restrict__ wt_hi, const ushort_t* __restrict__ wt_lo,
    const ushort_t* __restrict__ wa_hi, const ushort_t* __restrict__ wa_lo,
    ushort_t* __restrict__ t_hi, ushort_t* __restrict__ t_lo)
{
    __shared__ __attribute__((aligned(16))) char smem[49152];
    ushort_t* s_hsh = (ushort_t*)smem;             // [128][64]
    ushort_t* s_hsl = (ushort_t*)(smem + 16384);   // [128][64]
    ushort_t* s_wth = (ushort_t*)(smem + 32768);   // [64][64]
    ushort_t* s_wtl = (ushort_t*)(smem + 40960);   // [64][64]
    ushort_t* s_t1h = (ushort_t*)smem;             // aliases (phase 2)
    ushort_t* s_t1l = (ushort_t*)(smem + 16384);
    ushort_t* s_wah = (ushort_t*)(smem + 32768);
    ushort_t* s_wal = (ushort_t*)(smem + 40960);

    const int bid   = blockIdx.x;
    const int ntile = bid & 7;
    const int h     = (bid >> 3) % HEADS;
    const int b     = bid / (8 * HEADS);
    const int n0    = ntile * 128;
    const int tid   = threadIdx.x;
    const int w     = tid >> 6;
    const int lane  = tid & 63;
    const int q     = lane >> 4;
    const int mr    = lane & 15;
    const int lrow  = lane >> 3;
    const int lcol  = (lane & 7) * 8;

    const ushort_t* hsh_g = hs_hi + (size_t)b * SEQ * HID_;
    const ushort_t* hsl_g = hs_lo + (size_t)b * SEQ * HID_;
    const ushort_t* wth_g = wt_hi + (size_t)h * LORA * HID_;
    const ushort_t* wtl_g = wt_lo + (size_t)h * LORA * HID_;
    const ushort_t* wah_g = wa_hi + (size_t)h * HDIM * LORA;
    const ushort_t* wal_g = wa_lo + (size_t)h * HDIM * LORA;

    const f32x4 z4 = {0.f, 0.f, 0.f, 0.f};
    f32x4 accB[2][4];
    #pragma unroll
    for (int mt = 0; mt < 2; ++mt)
        #pragma unroll
        for (int et = 0; et < 4; ++et) accB[mt][et] = z4;

    for (int lc = 0; lc < 4; ++lc) {
        const int l0g = lc * 64;

        f32x4 accA[2][4];
        #pragma unroll
        for (int mt = 0; mt < 2; ++mt)
            #pragma unroll
            for (int lt = 0; lt < 4; ++lt) accA[mt][lt] = z4;

        for (int rd = 0; rd < 12; ++rd) {
            const int k0 = rd * 64;
            __syncthreads();
            #pragma unroll
            for (int tt = 0; tt < 4; ++tt) {
                int r0 = w * 32 + tt * 8;
                GLD16(hsh_g + (size_t)(n0 + r0 + lrow) * HID_ + k0 + lcol, s_hsh + r0 * 64);
                GLD16(hsl_g + (size_t)(n0 + r0 + lrow) * HID_ + k0 + lcol, s_hsl + r0 * 64);
            }
            #pragma unroll
            for (int tt = 0; tt < 2; ++tt) {
                int r0 = w * 16 + tt * 8;
                GLD16(wth_g + (size_t)(l0g + r0 + lrow) * HID_ + k0 + lcol, s_wth + r0 * 64);
                GLD16(wtl_g + (size_t)(l0g + r0 + lrow) * HID_ + k0 + lcol, s_wtl + r0 * 64);
            }
            __syncthreads();

            #pragma unroll
            for (int ks = 0; ks < 2; ++ks) {
                bf16x8 ah[2], al[2], bh[4], bl[4];
                #pragma unroll
                for (int mt = 0; mt < 2; ++mt) {
                    int off = (w * 32 + mt * 16 + mr) * 64 + ks * 32 + q * 8;
                    ah[mt] = *(const bf16x8*)(s_hsh + off);
                    al[mt] = *(const bf16x8*)(s_hsl + off);
                }
                #pragma unroll
                for (int lt = 0; lt < 4; ++lt) {
                    int off = (lt * 16 + mr) * 64 + ks * 32 + q * 8;
                    bh[lt] = *(const bf16x8*)(s_wth + off);
                    bl[lt] = *(const bf16x8*)(s_wtl + off);
                }
                #pragma unroll
                for (int mt = 0; mt < 2; ++mt) {
                    #pragma unroll
                    for (int lt = 0; lt < 4; ++lt) {
                        accA[mt][lt] = __builtin_amdgcn_mfma_f32_16x16x32_bf16(ah[mt], bh[lt], accA[mt][lt], 0, 0, 0);
                        accA[mt][lt] = __builtin_amdgcn_mfma_f32_16x16x32_bf16(ah[mt], bl[lt], accA[mt][lt], 0, 0, 0);
                        accA[mt][lt] = __builtin_amdgcn_mfma_f32_16x16x32_bf16(al[mt], bh[lt], accA[mt][lt], 0, 0, 0);
                    }
                }
            }
        }
        __syncthreads();

        #pragma unroll
        for (int mt = 0; mt < 2; ++mt) {
            #pragma unroll
            for (int lt = 0; lt < 4; ++lt) {
                #pragma unroll
                for (int r = 0; r < 4; ++r) {
                    int nl = w * 32 + mt * 16 + q * 4 + r;
                    int ll = lt * 16 + mr;
                    float v = accA[mt][lt][r];
                    unsigned short hv = f2bf(v);
                    s_t1h[nl * 64 + ll] = hv;
                    s_t1l[nl * 64 + ll] = f2bf(v - bf2f(hv));
                }
            }
        }
        #pragma unroll
        for (int tt = 0; tt < 2; ++tt) {
            int r0 = w * 16 + tt * 8;
            GLD16(wah_g + (size_t)(r0 + lrow) * LORA + l0g + lcol, s_wah + r0 * 64);
            GLD16(wal_g + (size_t)(r0 + lrow) * LORA + l0g + lcol, s_wal + r0 * 64);
        }
        __syncthreads();

        #pragma unroll
        for (int ks = 0; ks < 2; ++ks) {
            bf16x8 ah[2], al[2], bh[4], bl[4];
            #pragma unroll
            for (int mt = 0; mt < 2; ++mt) {
                int off = (w * 32 + mt * 16 + mr) * 64 + ks * 32 + q * 8;
                ah[mt] = *(const bf16x8*)(s_t1h + off);
                al[mt] = *(const bf16x8*)(s_t1l + off);
            }
            #pragma unroll
            for (int et = 0; et < 4; ++et) {
                int off = (et * 16 + mr) * 64 + ks * 32 + q * 8;
                bh[et] = *(const bf16x8*)(s_wah + off);
                bl[et] = *(const bf16x8*)(s_wal + off);
            }
            #pragma unroll
            for (int mt = 0; mt < 2; ++mt) {
                #pragma unroll
                for (int et = 0; et < 4; ++et) {
                    accB[mt][et] = __builtin_amdgcn_mfma_f32_16x16x32_bf16(ah[mt], bh[et], accB[mt][et], 0, 0, 0);
                    accB[mt][et] = __builtin_amdgcn_mfma_f32_16x16x32_bf16(ah[mt], bl[et], accB[mt][et], 0, 0, 0);
                    accB[mt][et] = __builtin_amdgcn_mfma_f32_16x16x32_bf16(al[mt], bh[et], accB[mt][et], 0, 0, 0);
                }
            }
        }
    }

    // epilogue: t as hi/lo bf16
    ushort_t* th = t_hi + (((size_t)b * HEADS + h) * SEQ + n0) * HDIM;
    ushort_t* tl = t_lo + (((size_t)b * HEADS + h) * SEQ + n0) * HDIM;
    #pragma unroll
    for (int mt = 0; mt < 2; ++mt) {
        #pragma unroll
        for (int et = 0; et < 4; ++et) {
            #pragma unroll
            for (int r = 0; r < 4; ++r) {
                int nl = w * 32 + mt * 16 + q * 4 + r;
                int e  = et * 16 + mr;
                float v = accB[mt][et][r];
                unsigned short hv = f2bf(v);
                th[(size_t)nl * HDIM + e] = hv;
                tl[(size_t)nl * HDIM + e] = f2bf(v - bf2f(hv));
            }
        }
    }
}

// ---------------------------------------------------------------------------
// Transpose t[bh][n][e] -> tT[bh][e][n] (hi and lo).  grid = 96*8 blocks,
// each handles one (bh, 128-row n-chunk) via a padded LDS tile.
// ---------------------------------------------------------------------------
__global__ __launch_bounds__(256) void transpose_kernel(
    const ushort_t* __restrict__ src_h, const ushort_t* __restrict__ src_l,
    ushort_t* __restrict__ dst_h, ushort_t* __restrict__ dst_l)
{
    __shared__ ushort_t s[128 * 72];   // stride 72 keeps 16B alignment, gathers 2-way
    const int bid = blockIdx.x;
    const int nc  = bid & 7;
    const int bh  = bid >> 3;
    const int n0  = nc * 128;
    const int tid = threadIdx.x;
    const int e   = tid & 63;          // gather: e = full lane id -> 32 banks, 2-way
    const int nn  = (tid >> 6) * 32;   // wave owns a 32-wide n chunk

    #pragma unroll
    for (int a = 0; a < 2; ++a) {
        const ushort_t* src = ((a == 0) ? src_h : src_l) + (size_t)bh * (SEQ * HDIM);
        ushort_t*       dst = ((a == 0) ? dst_h : dst_l) + (size_t)bh * (SEQ * HDIM);
        __syncthreads();
        #pragma unroll
        for (int k = 0; k < 4; ++k) {
            int flat = tid + k * 256;
            int row = flat >> 3;
            int c8  = (flat & 7) * 8;
            *(ushort8_t*)&s[row * 72 + c8] =
                *(const ushort8_t*)&src[(size_t)(n0 + row) * 64 + c8];
        }
        __syncthreads();
        ushort_t buf[32];
        #pragma unroll
        for (int k = 0; k < 32; ++k) buf[k] = s[(nn + k) * 72 + e];
        #pragma unroll
        for (int k = 0; k < 4; ++k)
            *(ushort8_t*)&dst[(size_t)e * SEQ + n0 + nn + k * 8] =
                *(const ushort8_t*)&buf[k * 8];
    }
}

// ---------------------------------------------------------------------------
// Flash attention via bf16x3 MFMA.  grid = B*HEADS*(SEQ/64), block 256.
// Wave w owns i-rows [i0+w*16, +16).  Q frags in registers for all 16 j-tiles.
// Per j-tile: stage K/VT hi/lo (GLD16) -> S MFMA -> online softmax in regs ->
// P hi/lo via per-wave LDS region (intra-wave, no barrier) -> PV MFMA.
// LDS 50 KB -> 3 blocks/CU.
// ---------------------------------------------------------------------------
__global__ __launch_bounds__(256) void attn_mfma(
    const ushort_t* __restrict__ t_hi, const ushort_t* __restrict__ t_lo,
    const ushort_t* __restrict__ tT_hi, const ushort_t* __restrict__ tT_lo,
    const int* __restrict__ mask, float* __restrict__ out)
{
    __shared__ __attribute__((aligned(16))) ushort_t s_kh[64 * 64];
    __shared__ __attribute__((aligned(16))) ushort_t s_kl[64 * 64];
    __shared__ __attribute__((aligned(16))) ushort_t s_vh[64 * 64];
    __shared__ __attribute__((aligned(16))) ushort_t s_vl[64 * 64];
    __shared__ __attribute__((aligned(16))) ushort_t s_ph[64 * 72];  // P, stride 72
    __shared__ __attribute__((aligned(16))) ushort_t s_pl[64 * 72];

    const int bid  = blockIdx.x;
    const int it   = bid & 15;
    const int h    = (bid >> 4) % HEADS;
    const int b    = bid / (16 * HEADS);
    const int i0   = it * 64;
    const int tid  = threadIdx.x;
    const int w    = tid >> 6;
    const int lane = tid & 63;
    const int q    = lane >> 4;
    const int mr   = lane & 15;
    const int lrow = lane >> 3;
    const int lcol = (lane & 7) * 8;

    const size_t bh = ((size_t)b * HEADS + h) * SEQ * HDIM;
    const ushort_t* th = t_hi + bh;    // [1024][64]
    const ushort_t* tl = t_lo + bh;
    const ushort_t* vh = tT_hi + bh;   // [64][1024]
    const ushort_t* vl = tT_lo + bh;
    const int* mk = mask + (size_t)b * SEQ;

    // Q fragments in registers: rows i0 + w*16 + mr
    bf16x8 qh[2], ql[2];
    #pragma unroll
    for (int ks = 0; ks < 2; ++ks) {
        size_t off = (size_t)(i0 + w * 16 + mr) * 64 + ks * 32 + q * 8;
        qh[ks] = *(const bf16x8*)(th + off);
        ql[ks] = *(const bf16x8*)(tl + off);
    }

    const f32x4 z4 = {0.f, 0.f, 0.f, 0.f};
    float m_[4], l_[4];
    f32x4 o[4];
    #pragma unroll
    for (int r = 0; r < 4; ++r) { m_[r] = -INFINITY; l_[r] = 0.f; }
    #pragma unroll
    for (int et = 0; et < 4; ++et) o[et] = z4;

    for (int jt6 = 0; jt6 < 16; ++jt6) {
        const int j0 = jt6 * 64;
        __syncthreads();   // prior iter's K/V readers done
        #pragma unroll
        for (int t2 = 0; t2 < 2; ++t2) {
            int r0 = w * 16 + t2 * 8;
            GLD16(th + (size_t)(j0 + r0 + lrow) * 64 + lcol,        s_kh + r0 * 64);
            GLD16(tl + (size_t)(j0 + r0 + lrow) * 64 + lcol,        s_kl + r0 * 64);
            GLD16(vh + (size_t)(r0 + lrow) * SEQ + j0 + lcol,       s_vh + r0 * 64);
            GLD16(vl + (size_t)(r0 + lrow) * SEQ + j0 + lcol,       s_vl + r0 * 64);
        }
        __syncthreads();   // staging visible

        // ---- S = Q . K^T : S[i=w*16+q*4+r][j=jt*16+mr] in s4[jt][r] ----
        f32x4 s4[4];
        #pragma unroll
        for (int jt = 0; jt < 4; ++jt) {
            s4[jt] = z4;
            #pragma unroll
            for (int ks = 0; ks < 2; ++ks) {
                int off = (jt * 16 + mr) * 64 + ks * 32 + q * 8;
                bf16x8 kh = *(const bf16x8*)(s_kh + off);
                bf16x8 kl = *(const bf16x8*)(s_kl + off);
                s4[jt] = __builtin_amdgcn_mfma_f32_16x16x32_bf16(qh[ks], kh, s4[jt], 0, 0, 0);
                s4[jt] = __builtin_amdgcn_mfma_f32_16x16x32_bf16(qh[ks], kl, s4[jt], 0, 0, 0);
                s4[jt] = __builtin_amdgcn_mfma_f32_16x16x32_bf16(ql[ks], kh, s4[jt], 0, 0, 0);
            }
        }

        bool jm[4];
        #pragma unroll
        for (int jt = 0; jt < 4; ++jt) jm[jt] = (mk[j0 + jt * 16 + mr] == 0);

        // ---- online softmax (rows across 16-lane groups; shfl width 16) ----
        float p[4][4];   // [jt][r]
        #pragma unroll
        for (int r = 0; r < 4; ++r) {
            float sv[4];
            #pragma unroll
            for (int jt = 0; jt < 4; ++jt)
                sv[jt] = jm[jt] ? -INFINITY : s4[jt][r] * SCALE;
            float mx = fmaxf(fmaxf(sv[0], sv[1]), fmaxf(sv[2], sv[3]));
            #pragma unroll
            for (int d = 1; d < 16; d <<= 1)
                mx = fmaxf(mx, __shfl_xor(mx, d, 16));
            float mnew = fmaxf(m_[r], mx);
            float alpha;
            if (mnew == -INFINITY) {
                alpha = 1.f;
                #pragma unroll
                for (int jt = 0; jt < 4; ++jt) p[jt][r] = 0.f;
            } else {
                alpha = (m_[r] == -INFINITY) ? 0.f : __expf(m_[r] - mnew);
                #pragma unroll
                for (int jt = 0; jt < 4; ++jt)
                    p[jt][r] = jm[jt] ? 0.f : __expf(sv[jt] - mnew);
            }
            float rs = p[0][r] + p[1][r] + p[2][r] + p[3][r];
            #pragma unroll
            for (int d = 1; d < 16; d <<= 1)
                rs += __shfl_xor(rs, d, 16);
            m_[r] = mnew;
            l_[r] = l_[r] * alpha + rs;
            #pragma unroll
            for (int et = 0; et < 4; ++et) o[et][r] *= alpha;
        }

        // ---- P -> per-wave LDS region (intra-wave only; no barrier) ----
        #pragma unroll
        for (int jt = 0; jt < 4; ++jt) {
            #pragma unroll
            for (int r = 0; r < 4; ++r) {
                int addr = (w * 16 + q * 4 + r) * 72 + jt * 16 + mr;
                float pv = p[jt][r];
                unsigned short hv = f2bf(pv);
                s_ph[addr] = hv;
                s_pl[addr] = f2bf(pv - bf2f(hv));
            }
        }

        // ---- O += P . V : A = P rows i, B = V^T rows e ----
        #pragma unroll
        for (int ks = 0; ks < 2; ++ks) {
            int poff = (w * 16 + mr) * 72 + ks * 32 + q * 8;
            bf16x8 ph = *(const bf16x8*)(s_ph + poff);
            bf16x8 pl = *(const bf16x8*)(s_pl + poff);
            #pragma unroll
            for (int et = 0; et < 4; ++et) {
                int voff = (et * 16 + mr) * 64 + ks * 32 + q * 8;
                bf16x8 vvh = *(const bf16x8*)(s_vh + voff);
                bf16x8 vvl = *(const bf16x8*)(s_vl + voff);
                o[et] = __builtin_amdgcn_mfma_f32_16x16x32_bf16(ph, vvh, o[et], 0, 0, 0);
                o[et] = __builtin_amdgcn_mfma_f32_16x16x32_bf16(ph, vvl, o[et], 0, 0, 0);
                o[et] = __builtin_amdgcn_mfma_f32_16x16x32_bf16(pl, vvh, o[et], 0, 0, 0);
            }
        }
    }

    // ---- epilogue: out[b][n=i0+w*16+q*4+r][h*64 + et*16+mr] ----
    #pragma unroll
    for (int r = 0; r < 4; ++r) {
        float inv = (l_[r] > 0.f) ? 1.f / l_[r] : 0.f;
        int n = i0 + w * 16 + q * 4 + r;
        #pragma unroll
        for (int et = 0; et < 4; ++et) {
            out[((size_t)b * SEQ + n) * (HEADS * HDIM) + h * HDIM + et * 16 + mr]
                = o[et][r] * inv;
        }
    }
}

extern "C" void kernel_launch(void* const* d_in, const int* in_sizes, int n_in,
                              void* d_out, int out_size, void* d_ws, size_t ws_size,
                              hipStream_t stream) {
    const float* hs   = (const float*)d_in[0];
    const int*   mask = (const int*)d_in[1];
    const float* Wt   = (const float*)d_in[2];
    const float* Wa   = (const float*)d_in[3];
    float* out = (float*)d_out;

    // workspace layout (total 60,555,264 B — same footprint as round 2):
    //  [0      , 12.58MB)  t_hi            (proj out, attn in)
    //  [12.58MB, 25.17MB)  t_lo
    //  [25.17MB, 37.75MB)  hs_hi  -> reused as tT_hi after proj
    //  [37.75MB, 50.33MB)  hs_lo  -> reused as tT_lo after proj
    //  [50.33MB, 55.05MB)  wt_hi
    //  [55.05MB, 59.77MB)  wt_lo
    //  [59.77MB, 60.16MB)  wa_hi
    //  [60.16MB, 60.56MB)  wa_lo
    char* ws = (char*)d_ws;
    ushort_t* t_hi  = (ushort_t*)ws;
    ushort_t* t_lo  = (ushort_t*)(ws + 12582912);
    ushort_t* hs_hi = (ushort_t*)(ws + 25165824);
    ushort_t* hs_lo = (ushort_t*)(ws + 37748736);
    ushort_t* wt_hi = (ushort_t*)(ws + 50331648);
    ushort_t* wt_lo = (ushort_t*)(ws + 55050240);
    ushort_t* wa_hi = (ushort_t*)(ws + 59768832);
    ushort_t* wa_lo = (ushort_t*)(ws + 60162048);
    ushort_t* tT_hi = hs_hi;   // hs splits are dead after proj
    ushort_t* tT_lo = hs_lo;

    split_kernel<<<1024, 256, 0, stream>>>((const float4*)hs, (ushort4*)hs_hi,
                                           (ushort4*)hs_lo, (BATCH * SEQ * HID_) / 4);
    split_kernel<<<1024, 256, 0, stream>>>((const float4*)Wt, (ushort4*)wt_hi,
                                           (ushort4*)wt_lo, (HEADS * LORA * HID_) / 4);
    split_kernel<<<192, 256, 0, stream>>>((const float4*)Wa, (ushort4*)wa_hi,
                                          (ushort4*)wa_lo, (HEADS * HDIM * LORA) / 4);

    proj_mfma<<<BATCH * HEADS * (SEQ / 128), 256, 0, stream>>>(
        hs_hi, hs_lo, wt_hi, wt_lo, wa_hi, wa_lo, t_hi, t_lo);

    transpose_kernel<<<BATCH * HEADS * (SEQ / 128), 256, 0, stream>>>(
        t_hi, t_lo, tT_hi, tT_lo);

    attn_mfma<<<BATCH * HEADS * (SEQ / 64), 256, 0, stream>>>(
        t_hi, t_lo, tT_hi, tT_lo, mask, out);
}

// Round 5
// 322.150 us; speedup vs baseline: 10.3711x; 1.5574x over previous
//
#include <hip/hip_runtime.h>
#include <math.h>

#define BATCH 8
#define SEQ   1024
#define HID_  768
#define HEADS 12
#define LORA  256
#define HDIM  64

// scale = HID ** -0.5
#define SCALE 0.03608439182435161f

typedef short bf16x8 __attribute__((ext_vector_type(8)));
typedef float f32x4  __attribute__((ext_vector_type(4)));
typedef unsigned short ushort_t;
typedef unsigned short ushort8_t __attribute__((ext_vector_type(8)));

__device__ __forceinline__ unsigned short f2bf(float x) {
    unsigned u = __float_as_uint(x);
    u += 0x7fff + ((u >> 16) & 1);          // round-to-nearest-even
    return (unsigned short)(u >> 16);
}
__device__ __forceinline__ float bf2f(unsigned short h) {
    return __uint_as_float(((unsigned)h) << 16);
}

// async global->LDS, 16B per lane, LDS dest = uniform base + lane*16
#define GLD16(g, l) __builtin_amdgcn_global_load_lds( \
    (const __attribute__((address_space(1))) void*)(g), \
    (__attribute__((address_space(3))) void*)(l), 16, 0, 0)

// XOR swizzle: 64-elem bf16 rows as 8 chunks of 8; global chunk c of row r is
// stored at LDS chunk c^(r&7).  Element offset for chunk c of row r:
#define SW(c, r) ((((c) ^ ((r) & 7)) << 3))

// ---------------------------------------------------------------------------
// Pre-pass split fp32 -> (hi, lo) bf16
// ---------------------------------------------------------------------------
__global__ __launch_bounds__(256) void split_kernel(
    const float4* __restrict__ src, ushort4* __restrict__ hi,
    ushort4* __restrict__ lo, int n4)
{
    int stride = gridDim.x * blockDim.x;
    for (int i = blockIdx.x * blockDim.x + threadIdx.x; i < n4; i += stride) {
        float4 v = src[i];
        ushort4 h, l;
        h.x = f2bf(v.x); l.x = f2bf(v.x - bf2f(h.x));
        h.y = f2bf(v.y); l.y = f2bf(v.y - bf2f(h.y));
        h.z = f2bf(v.z); l.z = f2bf(v.z - bf2f(h.z));
        h.w = f2bf(v.w); l.w = f2bf(v.w - bf2f(h.w));
        hi[i] = h; lo[i] = l;
    }
}

// ---------------------------------------------------------------------------
// Projection (round-3 numerics, swizzled LDS):
//   t1 = hs.(Wt)^T with 3-term hi/lo;  t = t1.(Wa)^T with 3-term hi/lo.
// grid = B*HEADS*(SEQ/128), block 256.  LDS 48 KB -> 3 blocks/CU.
// ---------------------------------------------------------------------------
__global__ __launch_bounds__(256, 3) void proj_mfma(
    const ushort_t* __restrict__ hs_hi, const ushort_t* __restrict__ hs_lo,
    const ushort_t* __restrict__ wt_hi, const ushort_t* __restrict__ wt_lo,
    const ushort_t* __restrict__ wa_hi, const ushort_t* __restrict__ wa_lo,
    ushort_t* __restrict__ t_hi, ushort_t* __restrict__ t_lo)
{
    __shared__ __attribute__((aligned(16))) char smem[49152];
    ushort_t* s_hsh = (ushort_t*)smem;             // [128][64]
    ushort_t* s_hsl = (ushort_t*)(smem + 16384);   // [128][64]
    ushort_t* s_wth = (ushort_t*)(smem + 32768);   // [64][64]
    ushort_t* s_wtl = (ushort_t*)(smem + 40960);   // [64][64]
    // phase-B aliases
    ushort_t* s_t1h = (ushort_t*)smem;             // [128][64]
    ushort_t* s_t1l = (ushort_t*)(smem + 16384);
    ushort_t* s_wah = (ushort_t*)(smem + 32768);
    ushort_t* s_wal = (ushort_t*)(smem + 40960);

    const int bid   = blockIdx.x;
    const int ntile = bid & 7;
    const int h     = (bid >> 3) % HEADS;
    const int b     = bid / (8 * HEADS);
    const int n0    = ntile * 128;
    const int tid   = threadIdx.x;
    const int w     = tid >> 6;
    const int lane  = tid & 63;
    const int q     = lane >> 4;
    const int mr    = lane & 15;
    const int lrow  = lane >> 3;                        // staging: 8 rows/GLD16
    const int gswz  = (((lane & 7) ^ lrow) & 7) * 8;    // swizzled global column

    const ushort_t* hsh_g = hs_hi + (size_t)b * SEQ * HID_;
    const ushort_t* hsl_g = hs_lo + (size_t)b * SEQ * HID_;
    const ushort_t* wth_g = wt_hi + (size_t)h * LORA * HID_;
    const ushort_t* wtl_g = wt_lo + (size_t)h * LORA * HID_;
    const ushort_t* wah_g = wa_hi + (size_t)h * HDIM * LORA;
    const ushort_t* wal_g = wa_lo + (size_t)h * HDIM * LORA;

    const f32x4 z4 = {0.f, 0.f, 0.f, 0.f};
    f32x4 accB[2][4];
    #pragma unroll
    for (int mt = 0; mt < 2; ++mt)
        #pragma unroll
        for (int et = 0; et < 4; ++et) accB[mt][et] = z4;

    for (int lc = 0; lc < 4; ++lc) {
        const int l0g = lc * 64;

        f32x4 accA[2][4];
        #pragma unroll
        for (int mt = 0; mt < 2; ++mt)
            #pragma unroll
            for (int lt = 0; lt < 4; ++lt) accA[mt][lt] = z4;

        for (int rd = 0; rd < 12; ++rd) {
            const int k0 = rd * 64;
            __syncthreads();
            #pragma unroll
            for (int tt = 0; tt < 4; ++tt) {           // hs hi/lo: 32 rows/wave
                int r0 = w * 32 + tt * 8;
                GLD16(hsh_g + (size_t)(n0 + r0 + lrow) * HID_ + k0 + gswz, s_hsh + r0 * 64);
                GLD16(hsl_g + (size_t)(n0 + r0 + lrow) * HID_ + k0 + gswz, s_hsl + r0 * 64);
            }
            #pragma unroll
            for (int tt = 0; tt < 2; ++tt) {           // wt hi/lo: 16 rows/wave
                int r0 = w * 16 + tt * 8;
                GLD16(wth_g + (size_t)(l0g + r0 + lrow) * HID_ + k0 + gswz, s_wth + r0 * 64);
                GLD16(wtl_g + (size_t)(l0g + r0 + lrow) * HID_ + k0 + gswz, s_wtl + r0 * 64);
            }
            __syncthreads();

            #pragma unroll
            for (int ks = 0; ks < 2; ++ks) {
                bf16x8 ah[2], al[2], bh[4], bl[4];
                #pragma unroll
                for (int mt = 0; mt < 2; ++mt) {
                    int off = (w * 32 + mt * 16 + mr) * 64 + SW(ks * 4 + q, mr);
                    ah[mt] = *(const bf16x8*)(s_hsh + off);
                    al[mt] = *(const bf16x8*)(s_hsl + off);
                }
                #pragma unroll
                for (int lt = 0; lt < 4; ++lt) {
                    int off = (lt * 16 + mr) * 64 + SW(ks * 4 + q, mr);
                    bh[lt] = *(const bf16x8*)(s_wth + off);
                    bl[lt] = *(const bf16x8*)(s_wtl + off);
                }
                #pragma unroll
                for (int mt = 0; mt < 2; ++mt) {
                    #pragma unroll
                    for (int lt = 0; lt < 4; ++lt) {
                        accA[mt][lt] = __builtin_amdgcn_mfma_f32_16x16x32_bf16(ah[mt], bh[lt], accA[mt][lt], 0, 0, 0);
                        accA[mt][lt] = __builtin_amdgcn_mfma_f32_16x16x32_bf16(ah[mt], bl[lt], accA[mt][lt], 0, 0, 0);
                        accA[mt][lt] = __builtin_amdgcn_mfma_f32_16x16x32_bf16(al[mt], bh[lt], accA[mt][lt], 0, 0, 0);
                    }
                }
            }
        }
        __syncthreads();   // stage-A reads done; aliases reusable

        // t1 hi/lo -> swizzled LDS (intra-wave rows only)
        #pragma unroll
        for (int mt = 0; mt < 2; ++mt) {
            #pragma unroll
            for (int lt = 0; lt < 4; ++lt) {
                #pragma unroll
                for (int r = 0; r < 4; ++r) {
                    int row = w * 32 + mt * 16 + q * 4 + r;
                    int col = lt * 16 + mr;
                    int addr = row * 64 + ((((col >> 3) ^ (row & 7)) << 3) | (col & 7));
                    float v = accA[mt][lt][r];
                    unsigned short hv = f2bf(v);
                    s_t1h[addr] = hv;
                    s_t1l[addr] = f2bf(v - bf2f(hv));
                }
            }
        }
        #pragma unroll
        for (int tt = 0; tt < 2; ++tt) {               // wa hi/lo: 16 rows/wave
            int r0 = w * 16 + tt * 8;
            GLD16(wah_g + (size_t)(r0 + lrow) * LORA + l0g + gswz, s_wah + r0 * 64);
            GLD16(wal_g + (size_t)(r0 + lrow) * LORA + l0g + gswz, s_wal + r0 * 64);
        }
        __syncthreads();

        #pragma unroll
        for (int ks = 0; ks < 2; ++ks) {
            bf16x8 ah[2], al[2], bh[4], bl[4];
            #pragma unroll
            for (int mt = 0; mt < 2; ++mt) {
                int off = (w * 32 + mt * 16 + mr) * 64 + SW(ks * 4 + q, mr);
                ah[mt] = *(const bf16x8*)(s_t1h + off);
                al[mt] = *(const bf16x8*)(s_t1l + off);
            }
            #pragma unroll
            for (int et = 0; et < 4; ++et) {
                int off = (et * 16 + mr) * 64 + SW(ks * 4 + q, mr);
                bh[et] = *(const bf16x8*)(s_wah + off);
                bl[et] = *(const bf16x8*)(s_wal + off);
            }
            #pragma unroll
            for (int mt = 0; mt < 2; ++mt) {
                #pragma unroll
                for (int et = 0; et < 4; ++et) {
                    accB[mt][et] = __builtin_amdgcn_mfma_f32_16x16x32_bf16(ah[mt], bh[et], accB[mt][et], 0, 0, 0);
                    accB[mt][et] = __builtin_amdgcn_mfma_f32_16x16x32_bf16(ah[mt], bl[et], accB[mt][et], 0, 0, 0);
                    accB[mt][et] = __builtin_amdgcn_mfma_f32_16x16x32_bf16(al[mt], bh[et], accB[mt][et], 0, 0, 0);
                }
            }
        }
    }

    // epilogue: t as hi/lo bf16
    ushort_t* th = t_hi + (((size_t)b * HEADS + h) * SEQ + n0) * HDIM;
    ushort_t* tl = t_lo + (((size_t)b * HEADS + h) * SEQ + n0) * HDIM;
    #pragma unroll
    for (int mt = 0; mt < 2; ++mt) {
        #pragma unroll
        for (int et = 0; et < 4; ++et) {
            #pragma unroll
            for (int r = 0; r < 4; ++r) {
                int nl = w * 32 + mt * 16 + q * 4 + r;
                int e  = et * 16 + mr;
                float v = accB[mt][et][r];
                unsigned short hv = f2bf(v);
                th[(size_t)nl * HDIM + e] = hv;
                tl[(size_t)nl * HDIM + e] = f2bf(v - bf2f(hv));
            }
        }
    }
}

// ---------------------------------------------------------------------------
// Transpose t[bh][n][e] -> tT[bh][e][n] (hi and lo).
// ---------------------------------------------------------------------------
__global__ __launch_bounds__(256) void transpose_kernel(
    const ushort_t* __restrict__ src_h, const ushort_t* __restrict__ src_l,
    ushort_t* __restrict__ dst_h, ushort_t* __restrict__ dst_l)
{
    __shared__ ushort_t s[128 * 72];
    const int bid = blockIdx.x;
    const int nc  = bid & 7;
    const int bh  = bid >> 3;
    const int n0  = nc * 128;
    const int tid = threadIdx.x;
    const int e   = tid & 63;
    const int nn  = (tid >> 6) * 32;

    #pragma unroll
    for (int a = 0; a < 2; ++a) {
        const ushort_t* src = ((a == 0) ? src_h : src_l) + (size_t)bh * (SEQ * HDIM);
        ushort_t*       dst = ((a == 0) ? dst_h : dst_l) + (size_t)bh * (SEQ * HDIM);
        __syncthreads();
        #pragma unroll
        for (int k = 0; k < 4; ++k) {
            int flat = tid + k * 256;
            int row = flat >> 3;
            int c8  = (flat & 7) * 8;
            *(ushort8_t*)&s[row * 72 + c8] =
                *(const ushort8_t*)&src[(size_t)(n0 + row) * 64 + c8];
        }
        __syncthreads();
        ushort_t buf[32];
        #pragma unroll
        for (int k = 0; k < 32; ++k) buf[k] = s[(nn + k) * 72 + e];
        #pragma unroll
        for (int k = 0; k < 4; ++k)
            *(ushort8_t*)&dst[(size_t)e * SEQ + n0 + nn + k * 8] =
                *(const ushort8_t*)&buf[k * 8];
    }
}

// ---------------------------------------------------------------------------
// Flash attention, S^T/O^T layout.  grid = B*HEADS*(SEQ/128), block 256.
// Row i lives on the 4 lanes {q*16+mr}; softmax reduces across q via
// __shfl_xor(16/32) (FIX for round 4).  S = 3-term hi/lo; PV = Ph.(Vh+Vl).
// LDS: kh+kl+vh+vl (32K) + swizzled P stride 72 (18.4K) = 50.4K -> 3 blk/CU.
// ---------------------------------------------------------------------------
__global__ __launch_bounds__(256, 3) void attn_mfma(
    const ushort_t* __restrict__ t_hi, const ushort_t* __restrict__ t_lo,
    const ushort_t* __restrict__ tT_hi, const ushort_t* __restrict__ tT_lo,
    const int* __restrict__ mask, float* __restrict__ out)
{
    __shared__ __attribute__((aligned(16))) ushort_t s_kh[64 * 64];
    __shared__ __attribute__((aligned(16))) ushort_t s_kl[64 * 64];
    __shared__ __attribute__((aligned(16))) ushort_t s_vh[64 * 64];
    __shared__ __attribute__((aligned(16))) ushort_t s_vl[64 * 64];
    __shared__ __attribute__((aligned(16))) ushort_t s_p [128 * 72];

    const int bid  = blockIdx.x;
    const int it   = bid & 7;
    const int h    = (bid >> 3) % HEADS;
    const int b    = bid / (8 * HEADS);
    const int i0   = it * 128;
    const int tid  = threadIdx.x;
    const int w    = tid >> 6;
    const int lane = tid & 63;
    const int q    = lane >> 4;
    const int mr   = lane & 15;
    const int lrow = lane >> 3;
    const int gswz = (((lane & 7) ^ lrow) & 7) * 8;

    const size_t bh = ((size_t)b * HEADS + h) * SEQ * HDIM;
    const ushort_t* th = t_hi + bh;    // [1024][64]
    const ushort_t* tl = t_lo + bh;
    const ushort_t* vh = tT_hi + bh;   // [64][1024]
    const ushort_t* vl = tT_lo + bh;
    const int* mk = mask + (size_t)b * SEQ;

    // Q hi/lo fragments, rows i = i0 + w*32 + mt*16 + mr (natural layout)
    bf16x8 qh[2][2], ql[2][2];
    #pragma unroll
    for (int mt = 0; mt < 2; ++mt)
        #pragma unroll
        for (int ks = 0; ks < 2; ++ks) {
            size_t off = (size_t)(i0 + w * 32 + mt * 16 + mr) * 64 + ks * 32 + q * 8;
            qh[mt][ks] = *(const bf16x8*)(th + off);
            ql[mt][ks] = *(const bf16x8*)(tl + off);
        }

    const f32x4 z4 = {0.f, 0.f, 0.f, 0.f};
    float m_[2] = {-INFINITY, -INFINITY};
    float l_[2] = {0.f, 0.f};
    f32x4 oT[2][4];
    #pragma unroll
    for (int mt = 0; mt < 2; ++mt)
        #pragma unroll
        for (int et = 0; et < 4; ++et) oT[mt][et] = z4;

    for (int jt6 = 0; jt6 < 16; ++jt6) {
        const int j0 = jt6 * 64;
        __syncthreads();
        #pragma unroll
        for (int t2 = 0; t2 < 2; ++t2) {
            int r0 = w * 16 + t2 * 8;
            GLD16(th + (size_t)(j0 + r0 + lrow) * 64 + gswz,  s_kh + r0 * 64);
            GLD16(tl + (size_t)(j0 + r0 + lrow) * 64 + gswz,  s_kl + r0 * 64);
            GLD16(vh + (size_t)(r0 + lrow) * SEQ + j0 + gswz, s_vh + r0 * 64);
            GLD16(vl + (size_t)(r0 + lrow) * SEQ + j0 + gswz, s_vl + r0 * 64);
        }
        __syncthreads();

        // ---- S^T = K.Q^T, 3-term: lane holds S[i=..mr][j=jt*16+q*4+r] ----
        float sv[2][16];
        #pragma unroll
        for (int jt = 0; jt < 4; ++jt) {
            f32x4 st[2] = {z4, z4};
            #pragma unroll
            for (int ks = 0; ks < 2; ++ks) {
                int off = (jt * 16 + mr) * 64 + SW(ks * 4 + q, mr);
                bf16x8 kh = *(const bf16x8*)(s_kh + off);
                bf16x8 kl = *(const bf16x8*)(s_kl + off);
                #pragma unroll
                for (int mt = 0; mt < 2; ++mt) {
                    st[mt] = __builtin_amdgcn_mfma_f32_16x16x32_bf16(kh, qh[mt][ks], st[mt], 0, 0, 0);
                    st[mt] = __builtin_amdgcn_mfma_f32_16x16x32_bf16(kl, qh[mt][ks], st[mt], 0, 0, 0);
                    st[mt] = __builtin_amdgcn_mfma_f32_16x16x32_bf16(kh, ql[mt][ks], st[mt], 0, 0, 0);
                }
            }
            int4 mv = *(const int4*)(mk + j0 + jt * 16 + q * 4);
            #pragma unroll
            for (int mt = 0; mt < 2; ++mt) {
                sv[mt][jt * 4 + 0] = (mv.x == 0) ? -INFINITY : st[mt][0] * SCALE;
                sv[mt][jt * 4 + 1] = (mv.y == 0) ? -INFINITY : st[mt][1] * SCALE;
                sv[mt][jt * 4 + 2] = (mv.z == 0) ? -INFINITY : st[mt][2] * SCALE;
                sv[mt][jt * 4 + 3] = (mv.w == 0) ? -INFINITY : st[mt][3] * SCALE;
            }
        }

        // ---- online softmax: row spread over 4 q-lanes -> reduce xor 16,32 ----
        #pragma unroll
        for (int mt = 0; mt < 2; ++mt) {
            float mx = sv[mt][0];
            #pragma unroll
            for (int k = 1; k < 16; ++k) mx = fmaxf(mx, sv[mt][k]);
            mx = fmaxf(mx, __shfl_xor(mx, 16));
            mx = fmaxf(mx, __shfl_xor(mx, 32));
            float mnew = fmaxf(m_[mt], mx);
            float alpha, p[16], rs;
            if (mnew == -INFINITY) {          // row fully masked so far
                alpha = 1.f; rs = 0.f;
                #pragma unroll
                for (int k = 0; k < 16; ++k) p[k] = 0.f;
            } else {
                alpha = (m_[mt] == -INFINITY) ? 0.f : __expf(m_[mt] - mnew);
                rs = 0.f;
                #pragma unroll
                for (int k = 0; k < 16; ++k) { p[k] = __expf(sv[mt][k] - mnew); rs += p[k]; }
            }
            rs += __shfl_xor(rs, 16);
            rs += __shfl_xor(rs, 32);
            m_[mt] = mnew;
            l_[mt] = l_[mt] * alpha + rs;
            #pragma unroll
            for (int et = 0; et < 4; ++et) oT[mt][et] *= alpha;

            // P row -> swizzled LDS (8-elem chunks; this write covers half a chunk)
            int row = w * 32 + mt * 16 + mr;
            #pragma unroll
            for (int jt = 0; jt < 4; ++jt) {
                ushort4 pk;
                pk.x = f2bf(p[jt * 4 + 0]); pk.y = f2bf(p[jt * 4 + 1]);
                pk.z = f2bf(p[jt * 4 + 2]); pk.w = f2bf(p[jt * 4 + 3]);
                int c = jt * 2 + (q >> 1);
                *(ushort4*)&s_p[row * 72 + ((c ^ (row & 7)) << 3) + (q & 1) * 4] = pk;
            }
        }

        // ---- O^T += V^T . P^T (intra-wave P; no barrier) ----
        #pragma unroll
        for (int ks = 0; ks < 2; ++ks) {
            bf16x8 pf[2];
            #pragma unroll
            for (int mt = 0; mt < 2; ++mt) {
                int row = w * 32 + mt * 16 + mr;
                pf[mt] = *(const bf16x8*)(s_p + row * 72 + SW(ks * 4 + q, row));
            }
            #pragma unroll
            for (int et = 0; et < 4; ++et) {
                int off = (et * 16 + mr) * 64 + SW(ks * 4 + q, mr);
                bf16x8 vvh = *(const bf16x8*)(s_vh + off);
                bf16x8 vvl = *(const bf16x8*)(s_vl + off);
                #pragma unroll
                for (int mt = 0; mt < 2; ++mt) {
                    oT[mt][et] = __builtin_amdgcn_mfma_f32_16x16x32_bf16(vvh, pf[mt], oT[mt][et], 0, 0, 0);
                    oT[mt][et] = __builtin_amdgcn_mfma_f32_16x16x32_bf16(vvl, pf[mt], oT[mt][et], 0, 0, 0);
                }
            }
        }
    }

    // ---- epilogue: lane holds O^T[e=et*16+q*4+r][i=i0+w*32+mt*16+mr] ----
    #pragma unroll
    for (int mt = 0; mt < 2; ++mt) {
        float inv = (l_[mt] > 0.f) ? 1.f / l_[mt] : 0.f;
        int n = i0 + w * 32 + mt * 16 + mr;
        #pragma unroll
        for (int et = 0; et < 4; ++et) {
            float4 v = {oT[mt][et][0] * inv, oT[mt][et][1] * inv,
                        oT[mt][et][2] * inv, oT[mt][et][3] * inv};
            *(float4*)&out[((size_t)b * SEQ + n) * (HEADS * HDIM) + h * HDIM + et * 16 + q * 4] = v;
        }
    }
}

extern "C" void kernel_launch(void* const* d_in, const int* in_sizes, int n_in,
                              void* d_out, int out_size, void* d_ws, size_t ws_size,
                              hipStream_t stream) {
    const float* hs   = (const float*)d_in[0];
    const int*   mask = (const int*)d_in[1];
    const float* Wt   = (const float*)d_in[2];
    const float* Wa   = (const float*)d_in[3];
    float* out = (float*)d_out;

    // workspace layout (60,555,264 B total — same as rounds 2-4):
    char* ws = (char*)d_ws;
    ushort_t* t_hi  = (ushort_t*)ws;                   // 12.58 MB
    ushort_t* t_lo  = (ushort_t*)(ws + 12582912);      // 12.58 MB
    ushort_t* hs_hi = (ushort_t*)(ws + 25165824);      // 12.58 MB -> tT_hi after proj
    ushort_t* hs_lo = (ushort_t*)(ws + 37748736);      // 12.58 MB -> tT_lo after proj
    ushort_t* wt_hi = (ushort_t*)(ws + 50331648);
    ushort_t* wt_lo = (ushort_t*)(ws + 55050240);
    ushort_t* wa_hi = (ushort_t*)(ws + 59768832);
    ushort_t* wa_lo = (ushort_t*)(ws + 60162048);
    ushort_t* tT_hi = hs_hi;   // hs splits dead after proj
    ushort_t* tT_lo = hs_lo;

    split_kernel<<<1024, 256, 0, stream>>>((const float4*)hs, (ushort4*)hs_hi,
                                           (ushort4*)hs_lo, (BATCH * SEQ * HID_) / 4);
    split_kernel<<<1024, 256, 0, stream>>>((const float4*)Wt, (ushort4*)wt_hi,
                                           (ushort4*)wt_lo, (HEADS * LORA * HID_) / 4);
    split_kernel<<<192, 256, 0, stream>>>((const float4*)Wa, (ushort4*)wa_hi,
                                          (ushort4*)wa_lo, (HEADS * HDIM * LORA) / 4);

    proj_mfma<<<BATCH * HEADS * (SEQ / 128), 256, 0, stream>>>(
        hs_hi, hs_lo, wt_hi, wt_lo, wa_hi, wa_lo, t_hi, t_lo);

    transpose_kernel<<<BATCH * HEADS * (SEQ / 128), 256, 0, stream>>>(
        t_hi, t_lo, tT_hi, tT_lo);

    attn_mfma<<<BATCH * HEADS * (SEQ / 128), 256, 0, stream>>>(
        t_hi, t_lo, tT_hi, tT_lo, mask, out);
}

// Round 6
// 260.814 us; speedup vs baseline: 12.8101x; 1.2352x over previous
//
#include <hip/hip_runtime.h>
#include <math.h>

#define BATCH 8
#define SEQ   1024
#define HID_  768
#define HEADS 12
#define LORA  256
#define HDIM  64

// scale = HID ** -0.5
#define SCALE 0.03608439182435161f

typedef _Float16 f16_t;
typedef _Float16 f16x4 __attribute__((ext_vector_type(4)));
typedef _Float16 f16x8 __attribute__((ext_vector_type(8)));
typedef float    f32x4 __attribute__((ext_vector_type(4)));
typedef unsigned short ushort_t;
typedef unsigned short ushort8_t __attribute__((ext_vector_type(8)));

// async global->LDS, 16B per lane, LDS dest = uniform base + lane*16
#define GLD16(g, l) __builtin_amdgcn_global_load_lds( \
    (const __attribute__((address_space(1))) void*)(g), \
    (__attribute__((address_space(3))) void*)(l), 16, 0, 0)

// XOR swizzle: 64-elem fp16 rows as 8 chunks of 8; global chunk c of row r is
// stored at LDS chunk c^(r&7).  Element offset for chunk c of row r:
#define SW(c, r) ((((c) ^ ((r) & 7)) << 3))

// ---------------------------------------------------------------------------
// Pre-pass: fp32 -> fp16 (RNE)
// ---------------------------------------------------------------------------
__global__ __launch_bounds__(256) void cvt_f16_kernel(
    const float4* __restrict__ src, f16x4* __restrict__ dst, int n4)
{
    int stride = gridDim.x * blockDim.x;
    for (int i = blockIdx.x * blockDim.x + threadIdx.x; i < n4; i += stride) {
        float4 v = src[i];
        f16x4 o = {(f16_t)v.x, (f16_t)v.y, (f16_t)v.z, (f16_t)v.w};
        dst[i] = o;
    }
}

// ---------------------------------------------------------------------------
// Projection, single-term fp16 MFMA:
//   t1 = hs_f16 . Wt_f16^T ;  t = t1_f16 . Wa_f16^T.
// grid = B*HEADS*(SEQ/128), block 256.  LDS 24 KB (swizzled, conflict-free).
// ---------------------------------------------------------------------------
__global__ __launch_bounds__(256, 4) void proj_mfma(
    const f16_t* __restrict__ hs_f, const f16_t* __restrict__ wt_f,
    const f16_t* __restrict__ wa_f, f16_t* __restrict__ t_f)
{
    __shared__ __attribute__((aligned(16))) char smem[24576];
    f16_t* s_hs = (f16_t*)smem;             // [128][64] stage A
    f16_t* s_wt = (f16_t*)(smem + 16384);   // [64][64]
    f16_t* s_t1 = (f16_t*)smem;             // [128][64] stage B (alias)
    f16_t* s_wa = (f16_t*)(smem + 16384);   // [64][64]  (alias)

    const int bid   = blockIdx.x;
    const int ntile = bid & 7;
    const int h     = (bid >> 3) % HEADS;
    const int b     = bid / (8 * HEADS);
    const int n0    = ntile * 128;
    const int tid   = threadIdx.x;
    const int w     = tid >> 6;
    const int lane  = tid & 63;
    const int q     = lane >> 4;
    const int mr    = lane & 15;
    const int lrow  = lane >> 3;                        // staging: 8 rows/GLD16
    const int gswz  = (((lane & 7) ^ lrow) & 7) * 8;    // swizzled global column

    const f16_t* hs_g = hs_f + (size_t)b * SEQ * HID_;
    const f16_t* wt_g = wt_f + (size_t)h * LORA * HID_;
    const f16_t* wa_g = wa_f + (size_t)h * HDIM * LORA;

    const f32x4 z4 = {0.f, 0.f, 0.f, 0.f};
    f32x4 accB[2][4];
    #pragma unroll
    for (int mt = 0; mt < 2; ++mt)
        #pragma unroll
        for (int et = 0; et < 4; ++et) accB[mt][et] = z4;

    for (int lc = 0; lc < 4; ++lc) {
        const int l0g = lc * 64;

        f32x4 accA[2][4];
        #pragma unroll
        for (int mt = 0; mt < 2; ++mt)
            #pragma unroll
            for (int lt = 0; lt < 4; ++lt) accA[mt][lt] = z4;

        for (int rd = 0; rd < 12; ++rd) {
            const int k0 = rd * 64;
            __syncthreads();   // prior readers of aliased LDS done
            #pragma unroll
            for (int tt = 0; tt < 4; ++tt) {           // hs: 32 rows/wave
                int r0 = w * 32 + tt * 8;
                GLD16(hs_g + (size_t)(n0 + r0 + lrow) * HID_ + k0 + gswz, s_hs + r0 * 64);
            }
            #pragma unroll
            for (int tt = 0; tt < 2; ++tt) {           // wt: 16 rows/wave
                int r0 = w * 16 + tt * 8;
                GLD16(wt_g + (size_t)(l0g + r0 + lrow) * HID_ + k0 + gswz, s_wt + r0 * 64);
            }
            __syncthreads();

            #pragma unroll
            for (int ks = 0; ks < 2; ++ks) {
                f16x8 a_[2], b_[4];
                #pragma unroll
                for (int mt = 0; mt < 2; ++mt)
                    a_[mt] = *(const f16x8*)(s_hs + (w * 32 + mt * 16 + mr) * 64 + SW(ks * 4 + q, mr));
                #pragma unroll
                for (int lt = 0; lt < 4; ++lt)
                    b_[lt] = *(const f16x8*)(s_wt + (lt * 16 + mr) * 64 + SW(ks * 4 + q, mr));
                #pragma unroll
                for (int mt = 0; mt < 2; ++mt)
                    #pragma unroll
                    for (int lt = 0; lt < 4; ++lt)
                        accA[mt][lt] = __builtin_amdgcn_mfma_f32_16x16x32_f16(a_[mt], b_[lt], accA[mt][lt], 0, 0, 0);
            }
        }
        __syncthreads();   // stage-A reads done; aliases reusable

        // t1 fp16 -> swizzled LDS (intra-wave rows only)
        #pragma unroll
        for (int mt = 0; mt < 2; ++mt) {
            #pragma unroll
            for (int lt = 0; lt < 4; ++lt) {
                #pragma unroll
                for (int r = 0; r < 4; ++r) {
                    int row = w * 32 + mt * 16 + q * 4 + r;
                    int col = lt * 16 + mr;
                    s_t1[row * 64 + ((((col >> 3) ^ (row & 7)) << 3) | (col & 7))]
                        = (f16_t)accA[mt][lt][r];
                }
            }
        }
        #pragma unroll
        for (int tt = 0; tt < 2; ++tt) {               // wa: 16 rows/wave
            int r0 = w * 16 + tt * 8;
            GLD16(wa_g + (size_t)(r0 + lrow) * LORA + l0g + gswz, s_wa + r0 * 64);
        }
        __syncthreads();

        #pragma unroll
        for (int ks = 0; ks < 2; ++ks) {
            f16x8 a_[2], b_[4];
            #pragma unroll
            for (int mt = 0; mt < 2; ++mt)
                a_[mt] = *(const f16x8*)(s_t1 + (w * 32 + mt * 16 + mr) * 64 + SW(ks * 4 + q, mr));
            #pragma unroll
            for (int et = 0; et < 4; ++et)
                b_[et] = *(const f16x8*)(s_wa + (et * 16 + mr) * 64 + SW(ks * 4 + q, mr));
            #pragma unroll
            for (int mt = 0; mt < 2; ++mt)
                #pragma unroll
                for (int et = 0; et < 4; ++et)
                    accB[mt][et] = __builtin_amdgcn_mfma_f32_16x16x32_f16(a_[mt], b_[et], accB[mt][et], 0, 0, 0);
        }
    }

    // epilogue: t fp16
    f16_t* tg = t_f + (((size_t)b * HEADS + h) * SEQ + n0) * HDIM;
    #pragma unroll
    for (int mt = 0; mt < 2; ++mt) {
        #pragma unroll
        for (int et = 0; et < 4; ++et) {
            #pragma unroll
            for (int r = 0; r < 4; ++r) {
                int nl = w * 32 + mt * 16 + q * 4 + r;
                int e  = et * 16 + mr;
                tg[(size_t)nl * HDIM + e] = (f16_t)accB[mt][et][r];
            }
        }
    }
}

// ---------------------------------------------------------------------------
// Transpose t[bh][n][e] -> tT[bh][e][n]  (fp16; byte-level via ushort)
// ---------------------------------------------------------------------------
__global__ __launch_bounds__(256) void transpose_kernel(
    const ushort_t* __restrict__ src, ushort_t* __restrict__ dst)
{
    __shared__ ushort_t s[128 * 72];
    const int bid = blockIdx.x;
    const int nc  = bid & 7;
    const int bh  = bid >> 3;
    const int n0  = nc * 128;
    const int tid = threadIdx.x;
    const int e   = tid & 63;
    const int nn  = (tid >> 6) * 32;

    const ushort_t* sp = src + (size_t)bh * (SEQ * HDIM);
    ushort_t*       dp = dst + (size_t)bh * (SEQ * HDIM);
    #pragma unroll
    for (int k = 0; k < 4; ++k) {
        int flat = tid + k * 256;
        int row = flat >> 3;
        int c8  = (flat & 7) * 8;
        *(ushort8_t*)&s[row * 72 + c8] =
            *(const ushort8_t*)&sp[(size_t)(n0 + row) * 64 + c8];
    }
    __syncthreads();
    ushort_t buf[32];
    #pragma unroll
    for (int k = 0; k < 32; ++k) buf[k] = s[(nn + k) * 72 + e];
    #pragma unroll
    for (int k = 0; k < 4; ++k)
        *(ushort8_t*)&dp[(size_t)e * SEQ + n0 + nn + k * 8] =
            *(const ushort8_t*)&buf[k * 8];
}

// ---------------------------------------------------------------------------
// Flash attention, S^T/O^T layout, single-term fp16 MFMA.
// grid = B*HEADS*(SEQ/128), block 256; row i on lanes {q*16+mr}, softmax
// reduced across q via __shfl_xor(16/32).  LDS 34.8 KB -> 4 blocks/CU.
// ---------------------------------------------------------------------------
__global__ __launch_bounds__(256, 4) void attn_mfma(
    const f16_t* __restrict__ t_f, const f16_t* __restrict__ tT_f,
    const int* __restrict__ mask, float* __restrict__ out)
{
    __shared__ __attribute__((aligned(16))) f16_t s_k[64 * 64];
    __shared__ __attribute__((aligned(16))) f16_t s_v[64 * 64];   // V^T tile
    __shared__ __attribute__((aligned(16))) f16_t s_p[128 * 72];

    const int bid  = blockIdx.x;
    const int it   = bid & 7;
    const int h    = (bid >> 3) % HEADS;
    const int b    = bid / (8 * HEADS);
    const int i0   = it * 128;
    const int tid  = threadIdx.x;
    const int w    = tid >> 6;
    const int lane = tid & 63;
    const int q    = lane >> 4;
    const int mr   = lane & 15;
    const int lrow = lane >> 3;
    const int gswz = (((lane & 7) ^ lrow) & 7) * 8;

    const size_t bh = ((size_t)b * HEADS + h) * SEQ * HDIM;
    const f16_t* th = t_f + bh;    // [1024][64]
    const f16_t* vh = tT_f + bh;   // [64][1024]
    const int* mk = mask + (size_t)b * SEQ;

    // Q fragments, rows i = i0 + w*32 + mt*16 + mr (natural layout)
    f16x8 qf[2][2];
    #pragma unroll
    for (int mt = 0; mt < 2; ++mt)
        #pragma unroll
        for (int ks = 0; ks < 2; ++ks)
            qf[mt][ks] = *(const f16x8*)(th + (size_t)(i0 + w * 32 + mt * 16 + mr) * 64
                                         + ks * 32 + q * 8);

    const f32x4 z4 = {0.f, 0.f, 0.f, 0.f};
    float m_[2] = {-INFINITY, -INFINITY};
    float l_[2] = {0.f, 0.f};
    f32x4 oT[2][4];
    #pragma unroll
    for (int mt = 0; mt < 2; ++mt)
        #pragma unroll
        for (int et = 0; et < 4; ++et) oT[mt][et] = z4;

    for (int jt6 = 0; jt6 < 16; ++jt6) {
        const int j0 = jt6 * 64;
        __syncthreads();
        #pragma unroll
        for (int t2 = 0; t2 < 2; ++t2) {
            int r0 = w * 16 + t2 * 8;
            GLD16(th + (size_t)(j0 + r0 + lrow) * 64 + gswz,  s_k + r0 * 64);
            GLD16(vh + (size_t)(r0 + lrow) * SEQ + j0 + gswz, s_v + r0 * 64);
        }
        __syncthreads();

        // ---- S^T = K.Q^T : lane holds S[i=..mr][j=jt*16+q*4+r] ----
        float sv[2][16];
        #pragma unroll
        for (int jt = 0; jt < 4; ++jt) {
            f32x4 st[2] = {z4, z4};
            #pragma unroll
            for (int ks = 0; ks < 2; ++ks) {
                f16x8 kf = *(const f16x8*)(s_k + (jt * 16 + mr) * 64 + SW(ks * 4 + q, mr));
                #pragma unroll
                for (int mt = 0; mt < 2; ++mt)
                    st[mt] = __builtin_amdgcn_mfma_f32_16x16x32_f16(kf, qf[mt][ks], st[mt], 0, 0, 0);
            }
            int4 mv = *(const int4*)(mk + j0 + jt * 16 + q * 4);
            #pragma unroll
            for (int mt = 0; mt < 2; ++mt) {
                sv[mt][jt * 4 + 0] = (mv.x == 0) ? -INFINITY : st[mt][0] * SCALE;
                sv[mt][jt * 4 + 1] = (mv.y == 0) ? -INFINITY : st[mt][1] * SCALE;
                sv[mt][jt * 4 + 2] = (mv.z == 0) ? -INFINITY : st[mt][2] * SCALE;
                sv[mt][jt * 4 + 3] = (mv.w == 0) ? -INFINITY : st[mt][3] * SCALE;
            }
        }

        // ---- online softmax: row spread over 4 q-lanes -> reduce xor 16,32 ----
        #pragma unroll
        for (int mt = 0; mt < 2; ++mt) {
            float mx = sv[mt][0];
            #pragma unroll
            for (int k = 1; k < 16; ++k) mx = fmaxf(mx, sv[mt][k]);
            mx = fmaxf(mx, __shfl_xor(mx, 16));
            mx = fmaxf(mx, __shfl_xor(mx, 32));
            float mnew = fmaxf(m_[mt], mx);
            float alpha, p[16], rs;
            if (mnew == -INFINITY) {          // row fully masked so far
                alpha = 1.f; rs = 0.f;
                #pragma unroll
                for (int k = 0; k < 16; ++k) p[k] = 0.f;
            } else {
                alpha = (m_[mt] == -INFINITY) ? 0.f : __expf(m_[mt] - mnew);
                rs = 0.f;
                #pragma unroll
                for (int k = 0; k < 16; ++k) { p[k] = __expf(sv[mt][k] - mnew); rs += p[k]; }
            }
            rs += __shfl_xor(rs, 16);
            rs += __shfl_xor(rs, 32);
            m_[mt] = mnew;
            l_[mt] = l_[mt] * alpha + rs;
            #pragma unroll
            for (int et = 0; et < 4; ++et) oT[mt][et] *= alpha;

            // P row -> swizzled LDS (half-chunk f16x4 writes)
            int row = w * 32 + mt * 16 + mr;
            #pragma unroll
            for (int jt = 0; jt < 4; ++jt) {
                f16x4 pk = {(f16_t)p[jt * 4 + 0], (f16_t)p[jt * 4 + 1],
                            (f16_t)p[jt * 4 + 2], (f16_t)p[jt * 4 + 3]};
                int c = jt * 2 + (q >> 1);
                *(f16x4*)&s_p[row * 72 + ((c ^ (row & 7)) << 3) + (q & 1) * 4] = pk;
            }
        }

        // ---- O^T += V^T . P^T (intra-wave P; no barrier) ----
        #pragma unroll
        for (int ks = 0; ks < 2; ++ks) {
            f16x8 pf[2];
            #pragma unroll
            for (int mt = 0; mt < 2; ++mt) {
                int row = w * 32 + mt * 16 + mr;
                pf[mt] = *(const f16x8*)(s_p + row * 72 + SW(ks * 4 + q, row));
            }
            #pragma unroll
            for (int et = 0; et < 4; ++et) {
                f16x8 vv = *(const f16x8*)(s_v + (et * 16 + mr) * 64 + SW(ks * 4 + q, mr));
                #pragma unroll
                for (int mt = 0; mt < 2; ++mt)
                    oT[mt][et] = __builtin_amdgcn_mfma_f32_16x16x32_f16(vv, pf[mt], oT[mt][et], 0, 0, 0);
            }
        }
    }

    // ---- epilogue: lane holds O^T[e=et*16+q*4+r][i=i0+w*32+mt*16+mr] ----
    #pragma unroll
    for (int mt = 0; mt < 2; ++mt) {
        float inv = (l_[mt] > 0.f) ? 1.f / l_[mt] : 0.f;
        int n = i0 + w * 32 + mt * 16 + mr;
        #pragma unroll
        for (int et = 0; et < 4; ++et) {
            float4 v = {oT[mt][et][0] * inv, oT[mt][et][1] * inv,
                        oT[mt][et][2] * inv, oT[mt][et][3] * inv};
            *(float4*)&out[((size_t)b * SEQ + n) * (HEADS * HDIM) + h * HDIM + et * 16 + q * 4] = v;
        }
    }
}

extern "C" void kernel_launch(void* const* d_in, const int* in_sizes, int n_in,
                              void* d_out, int out_size, void* d_ws, size_t ws_size,
                              hipStream_t stream) {
    const float* hs   = (const float*)d_in[0];
    const int*   mask = (const int*)d_in[1];
    const float* Wt   = (const float*)d_in[2];
    const float* Wa   = (const float*)d_in[3];
    float* out = (float*)d_out;

    // workspace layout (30,277,632 B total):
    //  [0      , 12.58MB)  t_f16            (proj out, attn in)
    //  [12.58MB, 25.17MB)  hs_f16 -> reused as tT_f16 after proj
    //  [25.17MB, 29.88MB)  wt_f16
    //  [29.88MB, 30.28MB)  wa_f16
    char* ws = (char*)d_ws;
    f16_t* t_f  = (f16_t*)ws;
    f16_t* hs_f = (f16_t*)(ws + 12582912);
    f16_t* wt_f = (f16_t*)(ws + 25165824);
    f16_t* wa_f = (f16_t*)(ws + 29884416);
    f16_t* tT_f = hs_f;   // hs_f16 dead after proj

    cvt_f16_kernel<<<1024, 256, 0, stream>>>((const float4*)hs, (f16x4*)hs_f,
                                             (BATCH * SEQ * HID_) / 4);
    cvt_f16_kernel<<<1024, 256, 0, stream>>>((const float4*)Wt, (f16x4*)wt_f,
                                             (HEADS * LORA * HID_) / 4);
    cvt_f16_kernel<<<192, 256, 0, stream>>>((const float4*)Wa, (f16x4*)wa_f,
                                            (HEADS * HDIM * LORA) / 4);

    proj_mfma<<<BATCH * HEADS * (SEQ / 128), 256, 0, stream>>>(
        hs_f, wt_f, wa_f, t_f);

    transpose_kernel<<<BATCH * HEADS * (SEQ / 128), 256, 0, stream>>>(
        (const ushort_t*)t_f, (ushort_t*)tT_f);

    attn_mfma<<<BATCH * HEADS * (SEQ / 128), 256, 0, stream>>>(
        t_f, tT_f, mask, out);
}

// Round 8
// 216.356 us; speedup vs baseline: 15.4425x; 1.2055x over previous
//
#include <hip/hip_runtime.h>
#include <math.h>

#define BATCH 8
#define SEQ   1024
#define HID_  768
#define HEADS 12
#define LORA  256
#define HDIM  64

// scale = HID ** -0.5 ; folded with log2(e) for exp2-based softmax
#define SCALE      0.03608439182435161f
#define SCALE_LOG2 0.05205863235888918f   // SCALE * 1.4426950408889634

typedef _Float16 f16_t;
typedef _Float16 f16x4 __attribute__((ext_vector_type(4)));
typedef _Float16 f16x8 __attribute__((ext_vector_type(8)));
typedef float    f32x4 __attribute__((ext_vector_type(4)));
typedef unsigned short ushort_t;
typedef unsigned short ushort8_t __attribute__((ext_vector_type(8)));

// async global->LDS, 16B per lane, LDS dest = uniform base + lane*16
#define GLD16(g, l) __builtin_amdgcn_global_load_lds( \
    (const __attribute__((address_space(1))) void*)(g), \
    (__attribute__((address_space(3))) void*)(l), 16, 0, 0)

// XOR swizzle for 64-elem f16 rows (8 chunks of 8): chunk c of row r at c^(r&7).
#define SW(c, r) ((((c) ^ ((r) & 7)) << 3))

// ---------------------------------------------------------------------------
// Fused pre-pass: fp32 -> fp16 for hs, Wt, Wa in one launch.
// ---------------------------------------------------------------------------
#define N4_HS (BATCH * SEQ * HID_ / 4)
#define N4_WT (HEADS * LORA * HID_ / 4)
#define N4_WA (HEADS * HDIM * LORA / 4)

__global__ __launch_bounds__(256) void cvt_all_kernel(
    const float4* __restrict__ hs, const float4* __restrict__ wt,
    const float4* __restrict__ wa, f16x4* __restrict__ hs_f,
    f16x4* __restrict__ wt_f, f16x4* __restrict__ wa_f)
{
    int stride = gridDim.x * blockDim.x;
    for (int i = blockIdx.x * blockDim.x + threadIdx.x;
         i < N4_HS + N4_WT + N4_WA; i += stride) {
        const float4* s; f16x4* d; int j;
        if (i < N4_HS)                { s = hs; d = hs_f; j = i; }
        else if (i < N4_HS + N4_WT)   { s = wt; d = wt_f; j = i - N4_HS; }
        else                          { s = wa; d = wa_f; j = i - N4_HS - N4_WT; }
        float4 v = s[j];
        f16x4 o = {(f16_t)v.x, (f16_t)v.y, (f16_t)v.z, (f16_t)v.w};
        d[j] = o;
    }
}

// ---------------------------------------------------------------------------
// Projection, single-term fp16 MFMA (unchanged from round 6).
// ---------------------------------------------------------------------------
__global__ __launch_bounds__(256, 4) void proj_mfma(
    const f16_t* __restrict__ hs_f, const f16_t* __restrict__ wt_f,
    const f16_t* __restrict__ wa_f, f16_t* __restrict__ t_f)
{
    __shared__ __attribute__((aligned(16))) char smem[24576];
    f16_t* s_hs = (f16_t*)smem;             // [128][64] stage A
    f16_t* s_wt = (f16_t*)(smem + 16384);   // [64][64]
    f16_t* s_t1 = (f16_t*)smem;             // [128][64] stage B (alias)
    f16_t* s_wa = (f16_t*)(smem + 16384);   // [64][64]  (alias)

    const int bid   = blockIdx.x;
    const int ntile = bid & 7;
    const int h     = (bid >> 3) % HEADS;
    const int b     = bid / (8 * HEADS);
    const int n0    = ntile * 128;
    const int tid   = threadIdx.x;
    const int w     = tid >> 6;
    const int lane  = tid & 63;
    const int q     = lane >> 4;
    const int mr    = lane & 15;
    const int lrow  = lane >> 3;
    const int gswz  = (((lane & 7) ^ lrow) & 7) * 8;

    const f16_t* hs_g = hs_f + (size_t)b * SEQ * HID_;
    const f16_t* wt_g = wt_f + (size_t)h * LORA * HID_;
    const f16_t* wa_g = wa_f + (size_t)h * HDIM * LORA;

    const f32x4 z4 = {0.f, 0.f, 0.f, 0.f};
    f32x4 accB[2][4];
    #pragma unroll
    for (int mt = 0; mt < 2; ++mt)
        #pragma unroll
        for (int et = 0; et < 4; ++et) accB[mt][et] = z4;

    for (int lc = 0; lc < 4; ++lc) {
        const int l0g = lc * 64;

        f32x4 accA[2][4];
        #pragma unroll
        for (int mt = 0; mt < 2; ++mt)
            #pragma unroll
            for (int lt = 0; lt < 4; ++lt) accA[mt][lt] = z4;

        for (int rd = 0; rd < 12; ++rd) {
            const int k0 = rd * 64;
            __syncthreads();
            #pragma unroll
            for (int tt = 0; tt < 4; ++tt) {
                int r0 = w * 32 + tt * 8;
                GLD16(hs_g + (size_t)(n0 + r0 + lrow) * HID_ + k0 + gswz, s_hs + r0 * 64);
            }
            #pragma unroll
            for (int tt = 0; tt < 2; ++tt) {
                int r0 = w * 16 + tt * 8;
                GLD16(wt_g + (size_t)(l0g + r0 + lrow) * HID_ + k0 + gswz, s_wt + r0 * 64);
            }
            __syncthreads();

            #pragma unroll
            for (int ks = 0; ks < 2; ++ks) {
                f16x8 a_[2], b_[4];
                #pragma unroll
                for (int mt = 0; mt < 2; ++mt)
                    a_[mt] = *(const f16x8*)(s_hs + (w * 32 + mt * 16 + mr) * 64 + SW(ks * 4 + q, mr));
                #pragma unroll
                for (int lt = 0; lt < 4; ++lt)
                    b_[lt] = *(const f16x8*)(s_wt + (lt * 16 + mr) * 64 + SW(ks * 4 + q, mr));
                #pragma unroll
                for (int mt = 0; mt < 2; ++mt)
                    #pragma unroll
                    for (int lt = 0; lt < 4; ++lt)
                        accA[mt][lt] = __builtin_amdgcn_mfma_f32_16x16x32_f16(a_[mt], b_[lt], accA[mt][lt], 0, 0, 0);
            }
        }
        __syncthreads();

        #pragma unroll
        for (int mt = 0; mt < 2; ++mt) {
            #pragma unroll
            for (int lt = 0; lt < 4; ++lt) {
                #pragma unroll
                for (int r = 0; r < 4; ++r) {
                    int row = w * 32 + mt * 16 + q * 4 + r;
                    int col = lt * 16 + mr;
                    s_t1[row * 64 + ((((col >> 3) ^ (row & 7)) << 3) | (col & 7))]
                        = (f16_t)accA[mt][lt][r];
                }
            }
        }
        #pragma unroll
        for (int tt = 0; tt < 2; ++tt) {
            int r0 = w * 16 + tt * 8;
            GLD16(wa_g + (size_t)(r0 + lrow) * LORA + l0g + gswz, s_wa + r0 * 64);
        }
        __syncthreads();

        #pragma unroll
        for (int ks = 0; ks < 2; ++ks) {
            f16x8 a_[2], b_[4];
            #pragma unroll
            for (int mt = 0; mt < 2; ++mt)
                a_[mt] = *(const f16x8*)(s_t1 + (w * 32 + mt * 16 + mr) * 64 + SW(ks * 4 + q, mr));
            #pragma unroll
            for (int et = 0; et < 4; ++et)
                b_[et] = *(const f16x8*)(s_wa + (et * 16 + mr) * 64 + SW(ks * 4 + q, mr));
            #pragma unroll
            for (int mt = 0; mt < 2; ++mt)
                #pragma unroll
                for (int et = 0; et < 4; ++et)
                    accB[mt][et] = __builtin_amdgcn_mfma_f32_16x16x32_f16(a_[mt], b_[et], accB[mt][et], 0, 0, 0);
        }
    }

    f16_t* tg = t_f + (((size_t)b * HEADS + h) * SEQ + n0) * HDIM;
    #pragma unroll
    for (int mt = 0; mt < 2; ++mt) {
        #pragma unroll
        for (int et = 0; et < 4; ++et) {
            #pragma unroll
            for (int r = 0; r < 4; ++r) {
                int nl = w * 32 + mt * 16 + q * 4 + r;
                int e  = et * 16 + mr;
                tg[(size_t)nl * HDIM + e] = (f16_t)accB[mt][et][r];
            }
        }
    }
}

// ---------------------------------------------------------------------------
// Transpose t[bh][n][e] -> tT[bh][e][n]
// ---------------------------------------------------------------------------
__global__ __launch_bounds__(256) void transpose_kernel(
    const ushort_t* __restrict__ src, ushort_t* __restrict__ dst)
{
    __shared__ ushort_t s[128 * 72];
    const int bid = blockIdx.x;
    const int nc  = bid & 7;
    const int bh  = bid >> 3;
    const int n0  = nc * 128;
    const int tid = threadIdx.x;
    const int e   = tid & 63;
    const int nn  = (tid >> 6) * 32;

    const ushort_t* sp = src + (size_t)bh * (SEQ * HDIM);
    ushort_t*       dp = dst + (size_t)bh * (SEQ * HDIM);
    #pragma unroll
    for (int k = 0; k < 4; ++k) {
        int flat = tid + k * 256;
        int row = flat >> 3;
        int c8  = (flat & 7) * 8;
        *(ushort8_t*)&s[row * 72 + c8] =
            *(const ushort8_t*)&sp[(size_t)(n0 + row) * 64 + c8];
    }
    __syncthreads();
    ushort_t buf[32];
    #pragma unroll
    for (int k = 0; k < 32; ++k) buf[k] = s[(nn + k) * 72 + e];
    #pragma unroll
    for (int k = 0; k < 4; ++k)
        *(ushort8_t*)&dp[(size_t)e * SEQ + n0 + nn + k * 8] =
            *(const ushort8_t*)&buf[k * 8];
}

// ---------------------------------------------------------------------------
// Flash attention, fixed-max exp2 softmax, j-split waves (mt=4).
// grid = B*HEADS*(SEQ/128), block 256.  Wave w: i-half ih=w>>1 (64 rows),
// j-half jh=w&1 (32 cols per tile).  S^T layout: lane (q,mr) holds
// S[i=i0+ih*64+mt*16+mr][j=jh*32+jt*16+q*4+r].  Lane-local ell partials;
// one cross-wave O/ell merge at the end.  LDS 34 KB, ~3 blocks/CU.
// ---------------------------------------------------------------------------
__global__ __launch_bounds__(256, 3) void attn_mfma(
    const f16_t* __restrict__ t_f, const f16_t* __restrict__ tT_f,
    const int* __restrict__ mask, float* __restrict__ out)
{
    __shared__ __attribute__((aligned(16))) char smem[34816];
    f16_t* s_k = (f16_t*)smem;              // [64 j][64 e] swizzled
    f16_t* s_v = (f16_t*)(smem + 8192);     // [64 e][64 j] swizzled
    f16_t* s_p = (f16_t*)(smem + 16384);    // [128 i][72]  plain stride 72
    float* s_m = (float*)smem;              // merge buffer alias (2*64*68 f32)

    const int bid  = blockIdx.x;
    const int it   = bid & 7;
    const int h    = (bid >> 3) % HEADS;
    const int b    = bid / (8 * HEADS);
    const int i0   = it * 128;
    const int tid  = threadIdx.x;
    const int w    = tid >> 6;
    const int lane = tid & 63;
    const int q    = lane >> 4;
    const int mr   = lane & 15;
    const int lrow = lane >> 3;
    const int gswz = (((lane & 7) ^ lrow) & 7) * 8;
    const int ih   = w >> 1;                // i-half (64 rows)
    const int jh   = w & 1;                 // j-half (32 cols)

    const size_t bh = ((size_t)b * HEADS + h) * SEQ * HDIM;
    const f16_t* th = t_f + bh;    // [1024][64]
    const f16_t* vh = tT_f + bh;   // [64][1024]
    const int* mk = mask + (size_t)b * SEQ;

    // Q fragments, rows i = i0 + ih*64 + mt*16 + mr, pre-scaled by SCALE*log2e
    f16x8 qf[4][2];
    #pragma unroll
    for (int mt = 0; mt < 4; ++mt)
        #pragma unroll
        for (int ks = 0; ks < 2; ++ks) {
            f16x8 v = *(const f16x8*)(th + (size_t)(i0 + ih * 64 + mt * 16 + mr) * 64
                                      + ks * 32 + q * 8);
            #pragma unroll
            for (int j = 0; j < 8; ++j) v[j] = v[j] * (f16_t)SCALE_LOG2;
            qf[mt][ks] = v;
        }

    const f32x4 z4 = {0.f, 0.f, 0.f, 0.f};
    float l_[4] = {0.f, 0.f, 0.f, 0.f};
    f32x4 oT[4][4];
    #pragma unroll
    for (int mt = 0; mt < 4; ++mt)
        #pragma unroll
        for (int et = 0; et < 4; ++et) oT[mt][et] = z4;

    for (int jt6 = 0; jt6 < 16; ++jt6) {
        const int j0 = jt6 * 64;
        __syncthreads();
        #pragma unroll
        for (int t2 = 0; t2 < 2; ++t2) {
            int r0 = w * 16 + t2 * 8;
            GLD16(th + (size_t)(j0 + r0 + lrow) * 64 + gswz,  s_k + r0 * 64);
            GLD16(vh + (size_t)(r0 + lrow) * SEQ + j0 + gswz, s_v + r0 * 64);
        }
        __syncthreads();

        // ---- S^T over the wave's j-half; softmax immediately per jt ----
        #pragma unroll
        for (int jt = 0; jt < 2; ++jt) {
            f32x4 st[4] = {z4, z4, z4, z4};
            #pragma unroll
            for (int ks = 0; ks < 2; ++ks) {
                f16x8 kf = *(const f16x8*)(s_k + (jh * 32 + jt * 16 + mr) * 64 + SW(ks * 4 + q, mr));
                #pragma unroll
                for (int mt = 0; mt < 4; ++mt)
                    st[mt] = __builtin_amdgcn_mfma_f32_16x16x32_f16(kf, qf[mt][ks], st[mt], 0, 0, 0);
            }
            int4 mv = *(const int4*)(mk + j0 + jh * 32 + jt * 16 + q * 4);
            #pragma unroll
            for (int mt = 0; mt < 4; ++mt) {
                float p0 = (mv.x == 0) ? 0.f : __builtin_amdgcn_exp2f(st[mt][0]);
                float p1 = (mv.y == 0) ? 0.f : __builtin_amdgcn_exp2f(st[mt][1]);
                float p2 = (mv.z == 0) ? 0.f : __builtin_amdgcn_exp2f(st[mt][2]);
                float p3 = (mv.w == 0) ? 0.f : __builtin_amdgcn_exp2f(st[mt][3]);
                l_[mt] += (p0 + p1) + (p2 + p3);
                f16x4 u4 = {(f16_t)p0, (f16_t)p1, (f16_t)p2, (f16_t)p3};
                *(f16x4*)&s_p[(ih * 64 + mt * 16 + mr) * 72 + jh * 32 + jt * 16 + q * 4] = u4;
            }
        }

        // ---- O^T += V^T . P^T over this wave's j-half (intra-wave P) ----
        f16x8 pf[4];
        #pragma unroll
        for (int mt = 0; mt < 4; ++mt)
            pf[mt] = *(const f16x8*)(s_p + (ih * 64 + mt * 16 + mr) * 72 + jh * 32 + q * 8);
        #pragma unroll
        for (int et = 0; et < 4; ++et) {
            f16x8 vv = *(const f16x8*)(s_v + (et * 16 + mr) * 64 + SW(jh * 4 + q, mr));
            #pragma unroll
            for (int mt = 0; mt < 4; ++mt)
                oT[mt][et] = __builtin_amdgcn_mfma_f32_16x16x32_f16(vv, pf[mt], oT[mt][et], 0, 0, 0);
        }
    }

    // ---- in-wave ell reduction over q-lanes ----
    #pragma unroll
    for (int mt = 0; mt < 4; ++mt) {
        l_[mt] += __shfl_xor(l_[mt], 16);
        l_[mt] += __shfl_xor(l_[mt], 32);
    }

    // ---- cross-wave merge (j-half pairs share i-rows) via LDS ----
    __syncthreads();                          // everyone done with s_k/s_v/s_p
    if (jh == 1) {
        float* dst = s_m + ((size_t)ih * 64 + lane) * 68;
        #pragma unroll
        for (int mt = 0; mt < 4; ++mt) {
            #pragma unroll
            for (int et = 0; et < 4; ++et)
                *(f32x4*)&dst[(mt * 4 + et) * 4] = oT[mt][et];
            dst[64 + mt] = l_[mt];
        }
    }
    __syncthreads();
    if (jh == 0) {
        const float* src = s_m + ((size_t)ih * 64 + lane) * 68;
        #pragma unroll
        for (int mt = 0; mt < 4; ++mt) {
            float lt = l_[mt] + src[64 + mt];
            float inv = (lt > 0.f) ? 1.f / lt : 0.f;
            int n = i0 + ih * 64 + mt * 16 + mr;
            #pragma unroll
            for (int et = 0; et < 4; ++et) {
                f32x4 o2 = *(const f32x4*)&src[(mt * 4 + et) * 4];
                float4 v = {(oT[mt][et][0] + o2[0]) * inv, (oT[mt][et][1] + o2[1]) * inv,
                            (oT[mt][et][2] + o2[2]) * inv, (oT[mt][et][3] + o2[3]) * inv};
                *(float4*)&out[((size_t)b * SEQ + n) * (HEADS * HDIM) + h * HDIM + et * 16 + q * 4] = v;
            }
        }
    }
}

extern "C" void kernel_launch(void* const* d_in, const int* in_sizes, int n_in,
                              void* d_out, int out_size, void* d_ws, size_t ws_size,
                              hipStream_t stream) {
    const float* hs   = (const float*)d_in[0];
    const int*   mask = (const int*)d_in[1];
    const float* Wt   = (const float*)d_in[2];
    const float* Wa   = (const float*)d_in[3];
    float* out = (float*)d_out;

    // workspace layout (30,277,632 B total):
    char* ws = (char*)d_ws;
    f16_t* t_f  = (f16_t*)ws;                  // 12.58 MB
    f16_t* hs_f = (f16_t*)(ws + 12582912);     // 12.58 MB -> tT after proj
    f16_t* wt_f = (f16_t*)(ws + 25165824);     //  4.72 MB
    f16_t* wa_f = (f16_t*)(ws + 29884416);     //  0.39 MB
    f16_t* tT_f = hs_f;                        // hs_f16 dead after proj

    cvt_all_kernel<<<1024, 256, 0, stream>>>(
        (const float4*)hs, (const float4*)Wt, (const float4*)Wa,
        (f16x4*)hs_f, (f16x4*)wt_f, (f16x4*)wa_f);

    proj_mfma<<<BATCH * HEADS * (SEQ / 128), 256, 0, stream>>>(
        hs_f, wt_f, wa_f, t_f);

    transpose_kernel<<<BATCH * HEADS * (SEQ / 128), 256, 0, stream>>>(
        (const ushort_t*)t_f, (ushort_t*)tT_f);

    attn_mfma<<<BATCH * HEADS * (SEQ / 128), 256, 0, stream>>>(
        t_f, tT_f, mask, out);
}

// Round 9
// 179.232 us; speedup vs baseline: 18.6410x; 1.2071x over previous
//
#include <hip/hip_runtime.h>
#include <math.h>

#define BATCH 8
#define SEQ   1024
#define HID_  768
#define HEADS 12
#define LORA  256
#define HDIM  64

// scale = HID ** -0.5 ; folded with log2(e) for exp2-based softmax
#define SCALE      0.03608439182435161f
#define SCALE_LOG2 0.05205863235888918f   // SCALE * 1.4426950408889634

typedef _Float16 f16_t;
typedef _Float16 f16x4 __attribute__((ext_vector_type(4)));
typedef _Float16 f16x8 __attribute__((ext_vector_type(8)));
typedef float    f32x4 __attribute__((ext_vector_type(4)));
typedef unsigned short ushort_t;

// async global->LDS, 16B per lane, LDS dest = uniform base + lane*16
#define GLD16(g, l) __builtin_amdgcn_global_load_lds( \
    (const __attribute__((address_space(1))) void*)(g), \
    (__attribute__((address_space(3))) void*)(l), 16, 0, 0)

// XOR swizzle for 64-elem f16 rows (8 chunks of 8): chunk c of row r at c^(r&7).
#define SW(c, r) ((((c) ^ ((r) & 7)) << 3))

// ---------------------------------------------------------------------------
// Fused pre-pass: fp32 -> fp16 for hs, Wt, Wa in one launch.
// ---------------------------------------------------------------------------
#define N4_HS (BATCH * SEQ * HID_ / 4)
#define N4_WT (HEADS * LORA * HID_ / 4)
#define N4_WA (HEADS * HDIM * LORA / 4)

__global__ __launch_bounds__(256) void cvt_all_kernel(
    const float4* __restrict__ hs, const float4* __restrict__ wt,
    const float4* __restrict__ wa, f16x4* __restrict__ hs_f,
    f16x4* __restrict__ wt_f, f16x4* __restrict__ wa_f)
{
    int stride = gridDim.x * blockDim.x;
    for (int i = blockIdx.x * blockDim.x + threadIdx.x;
         i < N4_HS + N4_WT + N4_WA; i += stride) {
        const float4* s; f16x4* d; int j;
        if (i < N4_HS)                { s = hs; d = hs_f; j = i; }
        else if (i < N4_HS + N4_WT)   { s = wt; d = wt_f; j = i - N4_HS; }
        else                          { s = wa; d = wa_f; j = i - N4_HS - N4_WT; }
        float4 v = s[j];
        f16x4 o = {(f16_t)v.x, (f16_t)v.y, (f16_t)v.z, (f16_t)v.w};
        d[j] = o;
    }
}

// ---------------------------------------------------------------------------
// Projection, fp16 MFMA, barrier-minimized:
//   2 passes over K=768, each covering 128 LoRA cols (accA[2][8]) ->
//   24 staging rounds (vs 48), ~58 barriers/block (vs ~104).
//   Epilogue stages accB through LDS and writes BOTH t and tT with
//   16B/lane vectorized stores (transpose kernel fused away).
// grid = B*HEADS*(SEQ/128), block 256.  LDS 32 KB.
// ---------------------------------------------------------------------------
__global__ __launch_bounds__(256, 3) void proj_mfma(
    const f16_t* __restrict__ hs_f, const f16_t* __restrict__ wt_f,
    const f16_t* __restrict__ wa_f, f16_t* __restrict__ t_f,
    f16_t* __restrict__ tT_f)
{
    __shared__ __attribute__((aligned(16))) char smem[32768];
    f16_t* s_hs = (f16_t*)smem;             // [128][64]  stage A
    f16_t* s_wt = (f16_t*)(smem + 16384);   // [128][64]  stage A (128 l-rows)
    f16_t* s_t1 = (f16_t*)smem;             // [128][64]  stage B (alias)
    f16_t* s_wa = (f16_t*)(smem + 16384);   // [64][64]   stage B (alias)
    f16_t* s_ob = (f16_t*)smem;             // [128][72]  epilogue (alias)

    const int bid   = blockIdx.x;
    const int ntile = bid & 7;
    const int h     = (bid >> 3) % HEADS;
    const int b     = bid / (8 * HEADS);
    const int n0    = ntile * 128;
    const int tid   = threadIdx.x;
    const int w     = tid >> 6;
    const int lane  = tid & 63;
    const int q     = lane >> 4;
    const int mr    = lane & 15;
    const int lrow  = lane >> 3;
    const int gswz  = (((lane & 7) ^ lrow) & 7) * 8;

    const f16_t* hs_g = hs_f + (size_t)b * SEQ * HID_;
    const f16_t* wt_g = wt_f + (size_t)h * LORA * HID_;
    const f16_t* wa_g = wa_f + (size_t)h * HDIM * LORA;

    const f32x4 z4 = {0.f, 0.f, 0.f, 0.f};
    f32x4 accB[2][4];
    #pragma unroll
    for (int mt = 0; mt < 2; ++mt)
        #pragma unroll
        for (int et = 0; et < 4; ++et) accB[mt][et] = z4;

    for (int pass = 0; pass < 2; ++pass) {
        const int lp = pass * 128;

        f32x4 accA[2][8];
        #pragma unroll
        for (int mt = 0; mt < 2; ++mt)
            #pragma unroll
            for (int lt = 0; lt < 8; ++lt) accA[mt][lt] = z4;

        // ---- stage A: K = 768 in 12 rounds of 64; 128 l-cols at once ----
        for (int rd = 0; rd < 12; ++rd) {
            const int k0 = rd * 64;
            __syncthreads();   // prior readers of aliased LDS done
            #pragma unroll
            for (int tt = 0; tt < 4; ++tt) {       // hs: 32 rows/wave
                int r0 = w * 32 + tt * 8;
                GLD16(hs_g + (size_t)(n0 + r0 + lrow) * HID_ + k0 + gswz, s_hs + r0 * 64);
            }
            #pragma unroll
            for (int tt = 0; tt < 4; ++tt) {       // wt: 32 rows/wave (128 total)
                int r0 = w * 32 + tt * 8;
                GLD16(wt_g + (size_t)(lp + r0 + lrow) * HID_ + k0 + gswz, s_wt + r0 * 64);
            }
            __syncthreads();

            #pragma unroll
            for (int ks = 0; ks < 2; ++ks) {
                f16x8 a_[2], b_[8];
                #pragma unroll
                for (int mt = 0; mt < 2; ++mt)
                    a_[mt] = *(const f16x8*)(s_hs + (w * 32 + mt * 16 + mr) * 64 + SW(ks * 4 + q, mr));
                #pragma unroll
                for (int lt = 0; lt < 8; ++lt)
                    b_[lt] = *(const f16x8*)(s_wt + (lt * 16 + mr) * 64 + SW(ks * 4 + q, mr));
                #pragma unroll
                for (int mt = 0; mt < 2; ++mt)
                    #pragma unroll
                    for (int lt = 0; lt < 8; ++lt)
                        accA[mt][lt] = __builtin_amdgcn_mfma_f32_16x16x32_f16(a_[mt], b_[lt], accA[mt][lt], 0, 0, 0);
            }
        }

        // ---- stage B: two 64-l sub-chunks of this pass ----
        #pragma unroll
        for (int sub = 0; sub < 2; ++sub) {
            const int l0g = lp + sub * 64;
            __syncthreads();   // stage-A / prior-sub readers done
            // t1 sub-chunk -> swizzled LDS (intra-wave rows only)
            #pragma unroll
            for (int mt = 0; mt < 2; ++mt) {
                #pragma unroll
                for (int j = 0; j < 4; ++j) {
                    #pragma unroll
                    for (int r = 0; r < 4; ++r) {
                        int row = w * 32 + mt * 16 + q * 4 + r;
                        int col = j * 16 + mr;
                        s_t1[row * 64 + ((((col >> 3) ^ (row & 7)) << 3) | (col & 7))]
                            = (f16_t)accA[mt][sub * 4 + j][r];
                    }
                }
            }
            #pragma unroll
            for (int tt = 0; tt < 2; ++tt) {       // wa: 16 rows/wave (64 total)
                int r0 = w * 16 + tt * 8;
                GLD16(wa_g + (size_t)(r0 + lrow) * LORA + l0g + gswz, s_wa + r0 * 64);
            }
            __syncthreads();

            #pragma unroll
            for (int ks = 0; ks < 2; ++ks) {
                f16x8 a_[2], b_[4];
                #pragma unroll
                for (int mt = 0; mt < 2; ++mt)
                    a_[mt] = *(const f16x8*)(s_t1 + (w * 32 + mt * 16 + mr) * 64 + SW(ks * 4 + q, mr));
                #pragma unroll
                for (int et = 0; et < 4; ++et)
                    b_[et] = *(const f16x8*)(s_wa + (et * 16 + mr) * 64 + SW(ks * 4 + q, mr));
                #pragma unroll
                for (int mt = 0; mt < 2; ++mt)
                    #pragma unroll
                    for (int et = 0; et < 4; ++et)
                        accB[mt][et] = __builtin_amdgcn_mfma_f32_16x16x32_f16(a_[mt], b_[et], accB[mt][et], 0, 0, 0);
            }
        }
    }

    // ---- epilogue: accB -> LDS tile -> vectorized t and tT writes ----
    __syncthreads();   // stage-B readers done; s_ob aliases s_t1/s_wa
    #pragma unroll
    for (int mt = 0; mt < 2; ++mt) {
        #pragma unroll
        for (int et = 0; et < 4; ++et) {
            #pragma unroll
            for (int r = 0; r < 4; ++r) {
                int row = w * 32 + mt * 16 + q * 4 + r;
                int col = et * 16 + mr;
                s_ob[row * 72 + col] = (f16_t)accB[mt][et][r];
            }
        }
    }
    __syncthreads();

    // t[b,h,n0+row][e]: 16B/lane, rows contiguous -> fully coalesced
    f16_t* tg = t_f + (((size_t)b * HEADS + h) * SEQ + n0) * HDIM;
    #pragma unroll
    for (int k = 0; k < 4; ++k) {
        int u = tid + k * 256;         // 1024 units of 8 f16
        int row = u >> 3, c8 = (u & 7) * 8;
        *(f16x8*)&tg[row * 64 + c8] = *(const f16x8*)&s_ob[row * 72 + c8];
    }
    // tT[b,h,e][n0+n]: gather column from LDS, 16B/lane stores
    f16_t* tTg = tT_f + ((size_t)b * HEADS + h) * SEQ * HDIM;
    #pragma unroll
    for (int k = 0; k < 4; ++k) {
        int u = tid + k * 256;
        int e = u & 63, n8 = (u >> 6) * 8;
        f16x8 v;
        #pragma unroll
        for (int j = 0; j < 8; ++j) v[j] = s_ob[(n8 + j) * 72 + e];
        *(f16x8*)&tTg[(size_t)e * SEQ + n0 + n8] = v;
    }
}

// ---------------------------------------------------------------------------
// Flash attention, fixed-max exp2 softmax, j-split waves (unchanged, round 8).
// ---------------------------------------------------------------------------
__global__ __launch_bounds__(256, 3) void attn_mfma(
    const f16_t* __restrict__ t_f, const f16_t* __restrict__ tT_f,
    const int* __restrict__ mask, float* __restrict__ out)
{
    __shared__ __attribute__((aligned(16))) char smem[34816];
    f16_t* s_k = (f16_t*)smem;              // [64 j][64 e] swizzled
    f16_t* s_v = (f16_t*)(smem + 8192);     // [64 e][64 j] swizzled
    f16_t* s_p = (f16_t*)(smem + 16384);    // [128 i][72]  plain stride 72
    float* s_m = (float*)smem;              // merge buffer alias (2*64*68 f32)

    const int bid  = blockIdx.x;
    const int it   = bid & 7;
    const int h    = (bid >> 3) % HEADS;
    const int b    = bid / (8 * HEADS);
    const int i0   = it * 128;
    const int tid  = threadIdx.x;
    const int w    = tid >> 6;
    const int lane = tid & 63;
    const int q    = lane >> 4;
    const int mr   = lane & 15;
    const int lrow = lane >> 3;
    const int gswz = (((lane & 7) ^ lrow) & 7) * 8;
    const int ih   = w >> 1;                // i-half (64 rows)
    const int jh   = w & 1;                 // j-half (32 cols)

    const size_t bh = ((size_t)b * HEADS + h) * SEQ * HDIM;
    const f16_t* th = t_f + bh;    // [1024][64]
    const f16_t* vh = tT_f + bh;   // [64][1024]
    const int* mk = mask + (size_t)b * SEQ;

    // Q fragments, rows i = i0 + ih*64 + mt*16 + mr, pre-scaled by SCALE*log2e
    f16x8 qf[4][2];
    #pragma unroll
    for (int mt = 0; mt < 4; ++mt)
        #pragma unroll
        for (int ks = 0; ks < 2; ++ks) {
            f16x8 v = *(const f16x8*)(th + (size_t)(i0 + ih * 64 + mt * 16 + mr) * 64
                                      + ks * 32 + q * 8);
            #pragma unroll
            for (int j = 0; j < 8; ++j) v[j] = v[j] * (f16_t)SCALE_LOG2;
            qf[mt][ks] = v;
        }

    const f32x4 z4 = {0.f, 0.f, 0.f, 0.f};
    float l_[4] = {0.f, 0.f, 0.f, 0.f};
    f32x4 oT[4][4];
    #pragma unroll
    for (int mt = 0; mt < 4; ++mt)
        #pragma unroll
        for (int et = 0; et < 4; ++et) oT[mt][et] = z4;

    for (int jt6 = 0; jt6 < 16; ++jt6) {
        const int j0 = jt6 * 64;
        __syncthreads();
        #pragma unroll
        for (int t2 = 0; t2 < 2; ++t2) {
            int r0 = w * 16 + t2 * 8;
            GLD16(th + (size_t)(j0 + r0 + lrow) * 64 + gswz,  s_k + r0 * 64);
            GLD16(vh + (size_t)(r0 + lrow) * SEQ + j0 + gswz, s_v + r0 * 64);
        }
        __syncthreads();

        // ---- S^T over the wave's j-half; softmax immediately per jt ----
        #pragma unroll
        for (int jt = 0; jt < 2; ++jt) {
            f32x4 st[4] = {z4, z4, z4, z4};
            #pragma unroll
            for (int ks = 0; ks < 2; ++ks) {
                f16x8 kf = *(const f16x8*)(s_k + (jh * 32 + jt * 16 + mr) * 64 + SW(ks * 4 + q, mr));
                #pragma unroll
                for (int mt = 0; mt < 4; ++mt)
                    st[mt] = __builtin_amdgcn_mfma_f32_16x16x32_f16(kf, qf[mt][ks], st[mt], 0, 0, 0);
            }
            int4 mv = *(const int4*)(mk + j0 + jh * 32 + jt * 16 + q * 4);
            #pragma unroll
            for (int mt = 0; mt < 4; ++mt) {
                float p0 = (mv.x == 0) ? 0.f : __builtin_amdgcn_exp2f(st[mt][0]);
                float p1 = (mv.y == 0) ? 0.f : __builtin_amdgcn_exp2f(st[mt][1]);
                float p2 = (mv.z == 0) ? 0.f : __builtin_amdgcn_exp2f(st[mt][2]);
                float p3 = (mv.w == 0) ? 0.f : __builtin_amdgcn_exp2f(st[mt][3]);
                l_[mt] += (p0 + p1) + (p2 + p3);
                f16x4 u4 = {(f16_t)p0, (f16_t)p1, (f16_t)p2, (f16_t)p3};
                *(f16x4*)&s_p[(ih * 64 + mt * 16 + mr) * 72 + jh * 32 + jt * 16 + q * 4] = u4;
            }
        }

        // ---- O^T += V^T . P^T over this wave's j-half (intra-wave P) ----
        f16x8 pf[4];
        #pragma unroll
        for (int mt = 0; mt < 4; ++mt)
            pf[mt] = *(const f16x8*)(s_p + (ih * 64 + mt * 16 + mr) * 72 + jh * 32 + q * 8);
        #pragma unroll
        for (int et = 0; et < 4; ++et) {
            f16x8 vv = *(const f16x8*)(s_v + (et * 16 + mr) * 64 + SW(jh * 4 + q, mr));
            #pragma unroll
            for (int mt = 0; mt < 4; ++mt)
                oT[mt][et] = __builtin_amdgcn_mfma_f32_16x16x32_f16(vv, pf[mt], oT[mt][et], 0, 0, 0);
        }
    }

    // ---- in-wave ell reduction over q-lanes ----
    #pragma unroll
    for (int mt = 0; mt < 4; ++mt) {
        l_[mt] += __shfl_xor(l_[mt], 16);
        l_[mt] += __shfl_xor(l_[mt], 32);
    }

    // ---- cross-wave merge (j-half pairs share i-rows) via LDS ----
    __syncthreads();                          // everyone done with s_k/s_v/s_p
    if (jh == 1) {
        float* dst = s_m + ((size_t)ih * 64 + lane) * 68;
        #pragma unroll
        for (int mt = 0; mt < 4; ++mt) {
            #pragma unroll
            for (int et = 0; et < 4; ++et)
                *(f32x4*)&dst[(mt * 4 + et) * 4] = oT[mt][et];
            dst[64 + mt] = l_[mt];
        }
    }
    __syncthreads();
    if (jh == 0) {
        const float* src = s_m + ((size_t)ih * 64 + lane) * 68;
        #pragma unroll
        for (int mt = 0; mt < 4; ++mt) {
            float lt = l_[mt] + src[64 + mt];
            float inv = (lt > 0.f) ? 1.f / lt : 0.f;
            int n = i0 + ih * 64 + mt * 16 + mr;
            #pragma unroll
            for (int et = 0; et < 4; ++et) {
                f32x4 o2 = *(const f32x4*)&src[(mt * 4 + et) * 4];
                float4 v = {(oT[mt][et][0] + o2[0]) * inv, (oT[mt][et][1] + o2[1]) * inv,
                            (oT[mt][et][2] + o2[2]) * inv, (oT[mt][et][3] + o2[3]) * inv};
                *(float4*)&out[((size_t)b * SEQ + n) * (HEADS * HDIM) + h * HDIM + et * 16 + q * 4] = v;
            }
        }
    }
}

extern "C" void kernel_launch(void* const* d_in, const int* in_sizes, int n_in,
                              void* d_out, int out_size, void* d_ws, size_t ws_size,
                              hipStream_t stream) {
    const float* hs   = (const float*)d_in[0];
    const int*   mask = (const int*)d_in[1];
    const float* Wt   = (const float*)d_in[2];
    const float* Wa   = (const float*)d_in[3];
    float* out = (float*)d_out;

    // workspace layout (42,860,544 B total) — tT no longer aliases hs
    // (proj now writes tT while other blocks still read hs):
    char* ws = (char*)d_ws;
    f16_t* t_f  = (f16_t*)ws;                  // 12.58 MB
    f16_t* tT_f = (f16_t*)(ws + 12582912);     // 12.58 MB
    f16_t* hs_f = (f16_t*)(ws + 25165824);     // 12.58 MB
    f16_t* wt_f = (f16_t*)(ws + 37748736);     //  4.72 MB
    f16_t* wa_f = (f16_t*)(ws + 42467328);     //  0.39 MB

    cvt_all_kernel<<<1024, 256, 0, stream>>>(
        (const float4*)hs, (const float4*)Wt, (const float4*)Wa,
        (f16x4*)hs_f, (f16x4*)wt_f, (f16x4*)wa_f);

    proj_mfma<<<BATCH * HEADS * (SEQ / 128), 256, 0, stream>>>(
        hs_f, wt_f, wa_f, t_f, tT_f);

    attn_mfma<<<BATCH * HEADS * (SEQ / 128), 256, 0, stream>>>(
        t_f, tT_f, mask, out);
}